// Round 6
// baseline (457.979 us; speedup 1.0000x reference)
//
#include <hip/hip_runtime.h>

#define N_NODES 50000
#define N_EDGES 800000

typedef __attribute__((ext_vector_type(8))) short short8;
typedef __attribute__((ext_vector_type(4))) float f32x4;
typedef __attribute__((ext_vector_type(4))) unsigned short ushort4v;
typedef __attribute__((ext_vector_type(8))) unsigned short ushort8v;

// ---------------- split-bf16 helpers ----------------
// f32 = hi(bf16) + lo(bf16) + O(2^-33). GEMM uses Ahi*Bhi + Ahi*Blo + Alo*Bhi.

__device__ inline void split_bf16(float f, unsigned short& hi, unsigned short& lo) {
    union { float f; unsigned u; } a; a.f = f;
    unsigned r = (a.u + 0x7fffu + ((a.u >> 16) & 1u)) >> 16;  // RNE to bf16
    hi = (unsigned short)r;
    union { unsigned u; float f; } b; b.u = r << 16;
    union { float f; unsigned u; } c; c.f = f - b.f;
    unsigned r2 = (c.u + 0x7fffu + ((c.u >> 16) & 1u)) >> 16;
    lo = (unsigned short)r2;
}

__device__ inline float bf2f(unsigned short u) {
    union { unsigned u; float f; } a; a.u = (unsigned)u << 16; return a.f;
}

// ---------------- CSR build ----------------

__global__ void count_kernel(const int* __restrict__ dst, int* __restrict__ cnt, int E) {
    int e = blockIdx.x * blockDim.x + threadIdx.x;
    if (e < E) atomicAdd(&cnt[dst[e]], 1);
}

// One-block exclusive scan over n counts (1024 thr, sequential chunks + block scan).
// cc is read (counts) then overwritten (cursor offsets); rowptr gets the same.
__global__ __launch_bounds__(1024) void scan_full_kernel(int* cc, int* __restrict__ rowptr,
                                                         int n, int E) {
    __shared__ int sums[1024];
    const int tid = threadIdx.x;
    const int CH = (n + 1023) / 1024;  // 49
    const int base = tid * CH;
    int s = 0;
    for (int i = 0; i < CH; ++i) {
        int idx = base + i;
        if (idx < n) s += cc[idx];
    }
    sums[tid] = s;
    __syncthreads();
    for (int off = 1; off < 1024; off <<= 1) {
        int t = (tid >= off) ? sums[tid - off] : 0;
        __syncthreads();
        sums[tid] += t;
        __syncthreads();
    }
    int run = sums[tid] - s;  // exclusive prefix of this chunk
    for (int i = 0; i < CH; ++i) {
        int idx = base + i;
        if (idx < n) {
            int c = cc[idx];     // read BEFORE overwrite (same buffer)
            rowptr[idx] = run;
            cc[idx] = run;       // cursor for fill
            run += c;
        }
    }
    if (tid == 0) rowptr[n] = E;
}

__global__ void fill_kernel(const int* __restrict__ src, const int* __restrict__ dst,
                            int* __restrict__ cursor, int* __restrict__ esrc, int E) {
    int e = blockIdx.x * blockDim.x + threadIdx.x;
    if (e < E) {
        int p = atomicAdd(&cursor[dst[e]], 1);
        esrc[p] = src[e];
    }
}

// ---------------- fused pack(W) + split(x) prep ----------------
// blocks [0,320): pack 6 weight mats into B-fragment hi/lo planes.
//   layout/mat: [plane][ct][ks][lane][j], elem = W[ks*32+(lane>>4)*8+j][ct*16+(lane&15)]
// blocks [320, 6570): split x into hi/lo bf16 planes.

__global__ void prep_kernel(const float* __restrict__ W0, const float* __restrict__ W1,
                            const float* __restrict__ W2, const float* __restrict__ W3,
                            const float* __restrict__ W4, const float* __restrict__ W5,
                            unsigned short* __restrict__ wout,
                            const float* __restrict__ x, unsigned short* __restrict__ xhi,
                            unsigned short* __restrict__ xlo) {
    if (blockIdx.x < 320) {
        int t = blockIdx.x * 256 + threadIdx.x;  // 0..81919
        const float* W; int D, local, half; size_t base;
        if (t < 65536) {
            int mat = t >> 14; local = t & 16383; D = 128; half = 16384;
            base = (size_t)mat * 32768;
            W = mat == 0 ? W0 : mat == 1 ? W1 : mat == 2 ? W2 : W3;
        } else {
            int m = (t - 65536) >> 13; local = (t - 65536) & 8191; D = 64; half = 8192;
            base = 131072 + (size_t)m * 16384;
            W = m == 0 ? W4 : W5;
        }
        int j = local & 7, lane = (local >> 3) & 63, ks = (local >> 9) & 3, ct = local >> 11;
        int k = ks * 32 + ((lane >> 4) << 3) + j;
        int n = (ct << 4) + (lane & 15);
        unsigned short hi, lo;
        split_bf16(W[k * D + n], hi, lo);
        wout[base + local] = hi;
        wout[base + half + local] = lo;
    } else {
        int t = (blockIdx.x - 320) * 256 + threadIdx.x;  // one float4 per thread
        if (t >= N_NODES * 32) return;
        float4 v = *(const float4*)(x + (size_t)t * 4);
        float vv[4] = {v.x, v.y, v.z, v.w};
        ushort4v h, l;
#pragma unroll
        for (int j = 0; j < 4; ++j) {
            unsigned short a, b;
            split_bf16(vv[j], a, b);
            h[j] = a; l[j] = b;
        }
        *(ushort4v*)(xhi + (size_t)t * 4) = h;
        *(ushort4v*)(xlo + (size_t)t * 4) = l;
    }
}

// ---------------- mean aggregation (CSR gather, bf16-hi plane) ----------------
// One 32-lane group per node (50k independent chains), 4-way interleaved
// neighbor loop (4 independent load chains). Lane covers 4 channels (8B loads).
// Output: split hi/lo bf16 agg planes.

__global__ __launch_bounds__(256, 8) void agg_kernel(
    const unsigned short* __restrict__ Hhi, const int* __restrict__ rowptr,
    const int* __restrict__ esrc,
    unsigned short* __restrict__ Ahi, unsigned short* __restrict__ Alo, int n) {
    int g = (blockIdx.x * blockDim.x + threadIdx.x) >> 5;
    int l32 = threadIdx.x & 31;
    if (g >= n) return;
    int beg = rowptr[g], end = rowptr[g + 1];
    float a0[4] = {0.f, 0.f, 0.f, 0.f}, a1[4] = {0.f, 0.f, 0.f, 0.f};
    float a2[4] = {0.f, 0.f, 0.f, 0.f}, a3[4] = {0.f, 0.f, 0.f, 0.f};
    int k = beg;
    for (; k + 4 <= end; k += 4) {
        int e0 = esrc[k], e1 = esrc[k + 1], e2 = esrc[k + 2], e3 = esrc[k + 3];
        ushort4v v0 = *(const ushort4v*)(Hhi + (size_t)e0 * 128 + l32 * 4);
        ushort4v v1 = *(const ushort4v*)(Hhi + (size_t)e1 * 128 + l32 * 4);
        ushort4v v2 = *(const ushort4v*)(Hhi + (size_t)e2 * 128 + l32 * 4);
        ushort4v v3 = *(const ushort4v*)(Hhi + (size_t)e3 * 128 + l32 * 4);
#pragma unroll
        for (int j = 0; j < 4; ++j) {
            a0[j] += bf2f(v0[j]); a1[j] += bf2f(v1[j]);
            a2[j] += bf2f(v2[j]); a3[j] += bf2f(v3[j]);
        }
    }
    for (; k < end; ++k) {
        int e0 = esrc[k];
        ushort4v v0 = *(const ushort4v*)(Hhi + (size_t)e0 * 128 + l32 * 4);
#pragma unroll
        for (int j = 0; j < 4; ++j) a0[j] += bf2f(v0[j]);
    }
    float inv = (end > beg) ? 1.0f / (float)(end - beg) : 0.0f;
    ushort4v mh, ml;
#pragma unroll
    for (int j = 0; j < 4; ++j) {
        float m = (a0[j] + a1[j] + a2[j] + a3[j]) * inv;
        unsigned short h, l;
        split_bf16(m, h, l);
        mh[j] = h; ml[j] = l;
    }
    *(ushort4v*)(Ahi + (size_t)g * 128 + l32 * 4) = mh;
    *(ushort4v*)(Alo + (size_t)g * 128 + l32 * 4) = ml;
}

// ---------------- dual GEMM via MFMA (plane inputs, verbatim staging) --------
// out = A1@W1 + A2@W2 + b (opt ReLU). BM=32, 256 thr = 4 waves.
// A1/A2 arrive pre-split as hi/lo bf16 planes -> staging is pure ushort8v
// copies. In-place safe: block stages only its own 32 rows before writing them.

template <int DOUT, bool RELU, bool SPLIT_OUT>
__global__ __launch_bounds__(256, 4) void gemm_planes(
    const unsigned short* __restrict__ A1hi, const unsigned short* __restrict__ A1lo,
    const unsigned short* __restrict__ A2hi, const unsigned short* __restrict__ A2lo,
    const unsigned short* __restrict__ B1p, const unsigned short* __restrict__ B2p,
    const float* __restrict__ bias, float* __restrict__ outf,
    unsigned short* __restrict__ outhi, unsigned short* __restrict__ outlo, int M) {
    constexpr int K = 128, BM = 32, KS = 4, CT = DOUT / 16, CPW = CT / 4;
    constexpr int PITCH = K + 8;
    constexpr int HALF = CT * KS * 512;
    __shared__ unsigned short As[2][2][BM * PITCH];  // [mat][hi/lo][row*PITCH+k]

    const int tid = threadIdx.x;
    const int r0 = blockIdx.x * BM;

    // ---- stage 4 planes verbatim (512 chunks of 8 bf16 per plane) ----
    const unsigned short* __restrict__ srcs[4] = {A1hi, A1lo, A2hi, A2lo};
#pragma unroll
    for (int s = 0; s < 4; ++s) {
#pragma unroll
        for (int c = 0; c < 2; ++c) {
            int chunk = tid + c * 256;
            int row = chunk >> 4;
            int c8 = (chunk & 15) * 8;
            int grow = r0 + row; if (grow >= M) grow = M - 1;
            *(ushort8v*)(&As[s >> 1][s & 1][row * PITCH + c8]) =
                *(const ushort8v*)(srcs[s] + (size_t)grow * K + c8);
        }
    }
    __syncthreads();

    // ---- MFMA ----
    const int wave = tid >> 6, lane = tid & 63;
    const int rl = lane & 15, quad = lane >> 4;

    f32x4 acc[2][CPW];
#pragma unroll
    for (int c = 0; c < CPW; ++c) {
        float bv = bias[(wave * CPW + c) * 16 + rl];
        acc[0][c] = (f32x4){bv, bv, bv, bv};
        acc[1][c] = acc[0][c];
    }

#pragma unroll
    for (int mat = 0; mat < 2; ++mat) {
        const unsigned short* __restrict__ Bp = mat ? B2p : B1p;
#pragma unroll
        for (int ks = 0; ks < KS; ++ks) {
            short8 a[2][2];
#pragma unroll
            for (int rt = 0; rt < 2; ++rt)
#pragma unroll
                for (int p = 0; p < 2; ++p)
                    a[rt][p] = *(const short8*)(&As[mat][p][(rt * 16 + rl) * PITCH + ks * 32 + quad * 8]);
            short8 b[CPW][2];
#pragma unroll
            for (int c = 0; c < CPW; ++c)
#pragma unroll
                for (int p = 0; p < 2; ++p)
                    b[c][p] = *(const short8*)(Bp + p * HALF +
                                               (((wave * CPW + c) * KS + ks) * 64 + lane) * 8);
#pragma unroll
            for (int rt = 0; rt < 2; ++rt)
#pragma unroll
                for (int c = 0; c < CPW; ++c) {
                    acc[rt][c] = __builtin_amdgcn_mfma_f32_16x16x32_bf16(a[rt][0], b[c][0], acc[rt][c], 0, 0, 0);
                    acc[rt][c] = __builtin_amdgcn_mfma_f32_16x16x32_bf16(a[rt][0], b[c][1], acc[rt][c], 0, 0, 0);
                    acc[rt][c] = __builtin_amdgcn_mfma_f32_16x16x32_bf16(a[rt][1], b[c][0], acc[rt][c], 0, 0, 0);
                }
        }
    }

    // ---- epilogue: C/D layout col=lane&15, row=quad*4+reg ----
#pragma unroll
    for (int rt = 0; rt < 2; ++rt)
#pragma unroll
        for (int c = 0; c < CPW; ++c) {
            int col = (wave * CPW + c) * 16 + rl;
            int rowb = r0 + rt * 16 + quad * 4;
#pragma unroll
            for (int r = 0; r < 4; ++r) {
                int rr = rowb + r;
                if (rr < M) {
                    float vv = acc[rt][c][r];
                    if (RELU) vv = fmaxf(vv, 0.f);
                    if (SPLIT_OUT) {
                        unsigned short h, l;
                        split_bf16(vv, h, l);
                        outhi[(size_t)rr * DOUT + col] = h;
                        outlo[(size_t)rr * DOUT + col] = l;
                    } else {
                        outf[(size_t)rr * DOUT + col] = vv;
                    }
                }
            }
        }
}

// ---------------- launch ----------------

extern "C" void kernel_launch(void* const* d_in, const int* in_sizes, int n_in,
                              void* d_out, int out_size, void* d_ws, size_t ws_size,
                              hipStream_t stream) {
    const float* x   = (const float*)d_in[0];
    const int* eidx  = (const int*)d_in[1];
    const int* src   = eidx;             // edge_index[0]
    const int* dst   = eidx + N_EDGES;   // edge_index[1]
    const float* Wl0 = (const float*)d_in[2];
    const float* b0  = (const float*)d_in[3];
    const float* Wr0 = (const float*)d_in[4];
    const float* Wl1 = (const float*)d_in[5];
    const float* b1  = (const float*)d_in[6];
    const float* Wr1 = (const float*)d_in[7];
    const float* Wl2 = (const float*)d_in[8];
    const float* b2  = (const float*)d_in[9];
    const float* Wr2 = (const float*)d_in[10];
    float* outp = (float*)d_out;

    // workspace (~55 MB): h planes updated in place each layer; agg planes scratch
    unsigned short* xhi  = (unsigned short*)d_ws;           // N*128 each
    unsigned short* xlo  = xhi + (size_t)N_NODES * 128;
    unsigned short* aghi = xlo + (size_t)N_NODES * 128;
    unsigned short* aglo = aghi + (size_t)N_NODES * 128;
    int* rowptr = (int*)(aglo + (size_t)N_NODES * 128);     // 50016 (padded)
    int* cursor = rowptr + 50016;                           // N
    int* esrc   = cursor + N_NODES;                         // E
    unsigned short* packw = (unsigned short*)(esrc + N_EDGES);  // 163840 bf16 (16B-aligned)
    unsigned short* Wl0p = packw;
    unsigned short* Wr0p = packw + 32768;
    unsigned short* Wl1p = packw + 65536;
    unsigned short* Wr1p = packw + 98304;
    unsigned short* Wl2p = packw + 131072;
    unsigned short* Wr2p = packw + 147456;

    // --- prep: weight pack + x split (one kernel, independent of CSR chain) ---
    prep_kernel<<<6570, 256, 0, stream>>>(Wl0, Wr0, Wl1, Wr1, Wl2, Wr2, packw, x, xhi, xlo);

    // --- CSR build (keyed by dst): memset + count + 1-block scan + fill ---
    hipMemsetAsync(cursor, 0, N_NODES * sizeof(int), stream);
    count_kernel<<<(N_EDGES + 255) / 256, 256, 0, stream>>>(dst, cursor, N_EDGES);
    scan_full_kernel<<<1, 1024, 0, stream>>>(cursor, rowptr, N_NODES, N_EDGES);
    fill_kernel<<<(N_EDGES + 255) / 256, 256, 0, stream>>>(src, dst, cursor, esrc, N_EDGES);

    const int aggGrid = (N_NODES * 32 + 255) / 256;   // 6250
    const int gemmGrid = (N_NODES + 31) / 32;         // 1563

    // layer 0: x -> x (in place, ReLU)
    agg_kernel<<<aggGrid, 256, 0, stream>>>(xhi, rowptr, esrc, aghi, aglo, N_NODES);
    gemm_planes<128, true, true><<<gemmGrid, 256, 0, stream>>>(
        aghi, aglo, xhi, xlo, Wl0p, Wr0p, b0, nullptr, xhi, xlo, N_NODES);
    // layer 1: x -> x (in place, ReLU)
    agg_kernel<<<aggGrid, 256, 0, stream>>>(xhi, rowptr, esrc, aghi, aglo, N_NODES);
    gemm_planes<128, true, true><<<gemmGrid, 256, 0, stream>>>(
        aghi, aglo, xhi, xlo, Wl1p, Wr1p, b1, nullptr, xhi, xlo, N_NODES);
    // layer 2: x -> out (f32, no ReLU, DOUT=64)
    agg_kernel<<<aggGrid, 256, 0, stream>>>(xhi, rowptr, esrc, aghi, aglo, N_NODES);
    gemm_planes<64, false, false><<<gemmGrid, 256, 0, stream>>>(
        aghi, aglo, xhi, xlo, Wl2p, Wr2p, b2, outp, nullptr, nullptr, N_NODES);
}

// Round 7
// 343.270 us; speedup vs baseline: 1.3342x; 1.3342x over previous
//
#include <hip/hip_runtime.h>

#define N_NODES 50000
#define N_EDGES 800000

typedef __attribute__((ext_vector_type(8))) short short8;
typedef __attribute__((ext_vector_type(4))) float f32x4;
typedef __attribute__((ext_vector_type(4))) unsigned short ushort4v;
typedef __attribute__((ext_vector_type(8))) unsigned short ushort8v;

// ---------------- split-bf16 helpers ----------------
// f32 = hi(bf16) + lo(bf16) + O(2^-33). GEMM uses Ahi*Bhi + Ahi*Blo + Alo*Bhi.

__device__ inline void split_bf16(float f, unsigned short& hi, unsigned short& lo) {
    union { float f; unsigned u; } a; a.f = f;
    unsigned r = (a.u + 0x7fffu + ((a.u >> 16) & 1u)) >> 16;  // RNE to bf16
    hi = (unsigned short)r;
    union { unsigned u; float f; } b; b.u = r << 16;
    union { float f; unsigned u; } c; c.f = f - b.f;
    unsigned r2 = (c.u + 0x7fffu + ((c.u >> 16) & 1u)) >> 16;
    lo = (unsigned short)r2;
}

__device__ inline float bf2f(unsigned short u) {
    union { unsigned u; float f; } a; a.u = (unsigned)u << 16; return a.f;
}

// ---------------- prep: pack(W) + split(x) + count(dst) ----------------
// blocks [0,320): pack 6 weight mats into B-fragment hi/lo planes.
//   layout/mat: [plane][ct][ks][lane][j], elem = W[ks*32+(lane>>4)*8+j][ct*16+(lane&15)]
// blocks [320,6570): split x into hi/lo bf16 planes.
// blocks [6570,9695): count edges per dst (cursor must be pre-zeroed).

__global__ void prep_kernel(const float* __restrict__ W0, const float* __restrict__ W1,
                            const float* __restrict__ W2, const float* __restrict__ W3,
                            const float* __restrict__ W4, const float* __restrict__ W5,
                            unsigned short* __restrict__ wout,
                            const float* __restrict__ x, unsigned short* __restrict__ xhi,
                            unsigned short* __restrict__ xlo,
                            const int* __restrict__ dst, int* __restrict__ cnt) {
    if (blockIdx.x < 320) {
        int t = blockIdx.x * 256 + threadIdx.x;  // 0..81919
        const float* W; int D, local, half; size_t base;
        if (t < 65536) {
            int mat = t >> 14; local = t & 16383; D = 128; half = 16384;
            base = (size_t)mat * 32768;
            W = mat == 0 ? W0 : mat == 1 ? W1 : mat == 2 ? W2 : W3;
        } else {
            int m = (t - 65536) >> 13; local = (t - 65536) & 8191; D = 64; half = 8192;
            base = 131072 + (size_t)m * 16384;
            W = m == 0 ? W4 : W5;
        }
        int j = local & 7, lane = (local >> 3) & 63, ks = (local >> 9) & 3, ct = local >> 11;
        int k = ks * 32 + ((lane >> 4) << 3) + j;
        int n = (ct << 4) + (lane & 15);
        unsigned short hi, lo;
        split_bf16(W[k * D + n], hi, lo);
        wout[base + local] = hi;
        wout[base + half + local] = lo;
    } else if (blockIdx.x < 6570) {
        int t = (blockIdx.x - 320) * 256 + threadIdx.x;  // one float4 per thread
        if (t >= N_NODES * 32) return;
        float4 v = *(const float4*)(x + (size_t)t * 4);
        float vv[4] = {v.x, v.y, v.z, v.w};
        ushort4v h, l;
#pragma unroll
        for (int j = 0; j < 4; ++j) {
            unsigned short a, b;
            split_bf16(vv[j], a, b);
            h[j] = a; l[j] = b;
        }
        *(ushort4v*)(xhi + (size_t)t * 4) = h;
        *(ushort4v*)(xlo + (size_t)t * 4) = l;
    } else {
        int e = (blockIdx.x - 6570) * 256 + threadIdx.x;
        if (e < N_EDGES) atomicAdd(&cnt[dst[e]], 1);
    }
}

// ---------------- CSR scan (hierarchical, coalesced — R5 design) ----------------

__global__ void scan_block_kernel(const int* __restrict__ cnt, int* __restrict__ rowptr,
                                  int* __restrict__ bsums, int n) {
    __shared__ int s[256];
    int tid = threadIdx.x;
    int i = blockIdx.x * 256 + tid;
    int v = (i < n) ? cnt[i] : 0;
    s[tid] = v;
    __syncthreads();
    for (int off = 1; off < 256; off <<= 1) {
        int t = (tid >= off) ? s[tid - off] : 0;
        __syncthreads();
        s[tid] += t;
        __syncthreads();
    }
    if (i < n) rowptr[i] = s[tid] - v;   // exclusive
    if (tid == 255) bsums[blockIdx.x] = s[255];
}

__global__ void scan_sums_kernel(int* bsums, int nb) {
    __shared__ int s[256];
    int tid = threadIdx.x;
    int v = (tid < nb) ? bsums[tid] : 0;
    s[tid] = v;
    __syncthreads();
    for (int off = 1; off < 256; off <<= 1) {
        int t = (tid >= off) ? s[tid - off] : 0;
        __syncthreads();
        s[tid] += t;
        __syncthreads();
    }
    if (tid < nb) bsums[tid] = s[tid] - v;  // exclusive, in place
}

__global__ void add_off_kernel(int* __restrict__ rowptr, const int* __restrict__ bsums,
                               int* __restrict__ cursor, int n, int E) {
    int i = blockIdx.x * blockDim.x + threadIdx.x;
    if (i < n) {
        int r = rowptr[i] + bsums[i >> 8];
        rowptr[i] = r;
        cursor[i] = r;
    }
    if (i == 0) rowptr[n] = E;
}

__global__ void fill_kernel(const int* __restrict__ src, const int* __restrict__ dst,
                            int* __restrict__ cursor, int* __restrict__ esrc, int E) {
    int e = blockIdx.x * blockDim.x + threadIdx.x;
    if (e < E) {
        int p = atomicAdd(&cursor[dst[e]], 1);
        esrc[p] = src[e];
    }
}

// ---------------- mean aggregation (CSR gather, bf16-hi plane) ----------------
// One 32-lane group per node (50k independent chains), 4-way interleaved
// neighbor loop (4 independent load chains). Lane covers 4 channels (8B loads).
// Output: split hi/lo bf16 agg planes.

__global__ __launch_bounds__(256, 8) void agg_kernel(
    const unsigned short* __restrict__ Hhi, const int* __restrict__ rowptr,
    const int* __restrict__ esrc,
    unsigned short* __restrict__ Ahi, unsigned short* __restrict__ Alo, int n) {
    int g = (blockIdx.x * blockDim.x + threadIdx.x) >> 5;
    int l32 = threadIdx.x & 31;
    if (g >= n) return;
    int beg = rowptr[g], end = rowptr[g + 1];
    float a0[4] = {0.f, 0.f, 0.f, 0.f}, a1[4] = {0.f, 0.f, 0.f, 0.f};
    float a2[4] = {0.f, 0.f, 0.f, 0.f}, a3[4] = {0.f, 0.f, 0.f, 0.f};
    int k = beg;
    for (; k + 4 <= end; k += 4) {
        int e0 = esrc[k], e1 = esrc[k + 1], e2 = esrc[k + 2], e3 = esrc[k + 3];
        ushort4v v0 = *(const ushort4v*)(Hhi + (size_t)e0 * 128 + l32 * 4);
        ushort4v v1 = *(const ushort4v*)(Hhi + (size_t)e1 * 128 + l32 * 4);
        ushort4v v2 = *(const ushort4v*)(Hhi + (size_t)e2 * 128 + l32 * 4);
        ushort4v v3 = *(const ushort4v*)(Hhi + (size_t)e3 * 128 + l32 * 4);
#pragma unroll
        for (int j = 0; j < 4; ++j) {
            a0[j] += bf2f(v0[j]); a1[j] += bf2f(v1[j]);
            a2[j] += bf2f(v2[j]); a3[j] += bf2f(v3[j]);
        }
    }
    for (; k < end; ++k) {
        int e0 = esrc[k];
        ushort4v v0 = *(const ushort4v*)(Hhi + (size_t)e0 * 128 + l32 * 4);
#pragma unroll
        for (int j = 0; j < 4; ++j) a0[j] += bf2f(v0[j]);
    }
    float inv = (end > beg) ? 1.0f / (float)(end - beg) : 0.0f;
    ushort4v mh, ml;
#pragma unroll
    for (int j = 0; j < 4; ++j) {
        float m = (a0[j] + a1[j] + a2[j] + a3[j]) * inv;
        unsigned short h, l;
        split_bf16(m, h, l);
        mh[j] = h; ml[j] = l;
    }
    *(ushort4v*)(Ahi + (size_t)g * 128 + l32 * 4) = mh;
    *(ushort4v*)(Alo + (size_t)g * 128 + l32 * 4) = ml;
}

// ---------------- dual GEMM via MFMA (plane inputs, verbatim staging) --------
// out = A1@W1 + A2@W2 + b (opt ReLU). BM=32, 256 thr = 4 waves.
// A1/A2 arrive pre-split as hi/lo bf16 planes -> staging is pure ushort8v
// copies. In-place safe: block stages only its own 32 rows before writing them.

template <int DOUT, bool RELU, bool SPLIT_OUT>
__global__ __launch_bounds__(256, 4) void gemm_planes(
    const unsigned short* __restrict__ A1hi, const unsigned short* __restrict__ A1lo,
    const unsigned short* __restrict__ A2hi, const unsigned short* __restrict__ A2lo,
    const unsigned short* __restrict__ B1p, const unsigned short* __restrict__ B2p,
    const float* __restrict__ bias, float* __restrict__ outf,
    unsigned short* __restrict__ outhi, unsigned short* __restrict__ outlo, int M) {
    constexpr int K = 128, BM = 32, KS = 4, CT = DOUT / 16, CPW = CT / 4;
    constexpr int PITCH = K + 8;
    constexpr int HALF = CT * KS * 512;
    __shared__ unsigned short As[2][2][BM * PITCH];  // [mat][hi/lo][row*PITCH+k]

    const int tid = threadIdx.x;
    const int r0 = blockIdx.x * BM;

    // ---- stage 4 planes verbatim (512 chunks of 8 bf16 per plane) ----
    const unsigned short* __restrict__ srcs[4] = {A1hi, A1lo, A2hi, A2lo};
#pragma unroll
    for (int s = 0; s < 4; ++s) {
#pragma unroll
        for (int c = 0; c < 2; ++c) {
            int chunk = tid + c * 256;
            int row = chunk >> 4;
            int c8 = (chunk & 15) * 8;
            int grow = r0 + row; if (grow >= M) grow = M - 1;
            *(ushort8v*)(&As[s >> 1][s & 1][row * PITCH + c8]) =
                *(const ushort8v*)(srcs[s] + (size_t)grow * K + c8);
        }
    }
    __syncthreads();

    // ---- MFMA ----
    const int wave = tid >> 6, lane = tid & 63;
    const int rl = lane & 15, quad = lane >> 4;

    f32x4 acc[2][CPW];
#pragma unroll
    for (int c = 0; c < CPW; ++c) {
        float bv = bias[(wave * CPW + c) * 16 + rl];
        acc[0][c] = (f32x4){bv, bv, bv, bv};
        acc[1][c] = acc[0][c];
    }

#pragma unroll
    for (int mat = 0; mat < 2; ++mat) {
        const unsigned short* __restrict__ Bp = mat ? B2p : B1p;
#pragma unroll
        for (int ks = 0; ks < KS; ++ks) {
            short8 a[2][2];
#pragma unroll
            for (int rt = 0; rt < 2; ++rt)
#pragma unroll
                for (int p = 0; p < 2; ++p)
                    a[rt][p] = *(const short8*)(&As[mat][p][(rt * 16 + rl) * PITCH + ks * 32 + quad * 8]);
            short8 b[CPW][2];
#pragma unroll
            for (int c = 0; c < CPW; ++c)
#pragma unroll
                for (int p = 0; p < 2; ++p)
                    b[c][p] = *(const short8*)(Bp + p * HALF +
                                               (((wave * CPW + c) * KS + ks) * 64 + lane) * 8);
#pragma unroll
            for (int rt = 0; rt < 2; ++rt)
#pragma unroll
                for (int c = 0; c < CPW; ++c) {
                    acc[rt][c] = __builtin_amdgcn_mfma_f32_16x16x32_bf16(a[rt][0], b[c][0], acc[rt][c], 0, 0, 0);
                    acc[rt][c] = __builtin_amdgcn_mfma_f32_16x16x32_bf16(a[rt][0], b[c][1], acc[rt][c], 0, 0, 0);
                    acc[rt][c] = __builtin_amdgcn_mfma_f32_16x16x32_bf16(a[rt][1], b[c][0], acc[rt][c], 0, 0, 0);
                }
        }
    }

    // ---- epilogue: C/D layout col=lane&15, row=quad*4+reg ----
#pragma unroll
    for (int rt = 0; rt < 2; ++rt)
#pragma unroll
        for (int c = 0; c < CPW; ++c) {
            int col = (wave * CPW + c) * 16 + rl;
            int rowb = r0 + rt * 16 + quad * 4;
#pragma unroll
            for (int r = 0; r < 4; ++r) {
                int rr = rowb + r;
                if (rr < M) {
                    float vv = acc[rt][c][r];
                    if (RELU) vv = fmaxf(vv, 0.f);
                    if (SPLIT_OUT) {
                        unsigned short h, l;
                        split_bf16(vv, h, l);
                        outhi[(size_t)rr * DOUT + col] = h;
                        outlo[(size_t)rr * DOUT + col] = l;
                    } else {
                        outf[(size_t)rr * DOUT + col] = vv;
                    }
                }
            }
        }
}

// ---------------- launch ----------------

extern "C" void kernel_launch(void* const* d_in, const int* in_sizes, int n_in,
                              void* d_out, int out_size, void* d_ws, size_t ws_size,
                              hipStream_t stream) {
    const float* x   = (const float*)d_in[0];
    const int* eidx  = (const int*)d_in[1];
    const int* src   = eidx;             // edge_index[0]
    const int* dst   = eidx + N_EDGES;   // edge_index[1]
    const float* Wl0 = (const float*)d_in[2];
    const float* b0  = (const float*)d_in[3];
    const float* Wr0 = (const float*)d_in[4];
    const float* Wl1 = (const float*)d_in[5];
    const float* b1  = (const float*)d_in[6];
    const float* Wr1 = (const float*)d_in[7];
    const float* Wl2 = (const float*)d_in[8];
    const float* b2  = (const float*)d_in[9];
    const float* Wr2 = (const float*)d_in[10];
    float* outp = (float*)d_out;

    // workspace (~55 MB): h planes updated in place each layer; agg planes scratch
    unsigned short* xhi  = (unsigned short*)d_ws;           // N*128 each
    unsigned short* xlo  = xhi + (size_t)N_NODES * 128;
    unsigned short* aghi = xlo + (size_t)N_NODES * 128;
    unsigned short* aglo = aghi + (size_t)N_NODES * 128;
    int* rowptr = (int*)(aglo + (size_t)N_NODES * 128);     // 50016 (padded)
    int* cursor = rowptr + 50016;                           // N
    int* esrc   = cursor + N_NODES;                         // E
    int* bsums  = esrc + N_EDGES;                           // 256
    unsigned short* packw = (unsigned short*)(bsums + 256); // 163840 bf16 (16B-aligned)
    unsigned short* Wl0p = packw;
    unsigned short* Wr0p = packw + 32768;
    unsigned short* Wl1p = packw + 65536;
    unsigned short* Wr1p = packw + 98304;
    unsigned short* Wl2p = packw + 131072;
    unsigned short* Wr2p = packw + 147456;

    // --- prep (pack W + split x + count dst) after zeroing counts ---
    hipMemsetAsync(cursor, 0, N_NODES * sizeof(int), stream);
    prep_kernel<<<9695, 256, 0, stream>>>(Wl0, Wr0, Wl1, Wr1, Wl2, Wr2, packw,
                                          x, xhi, xlo, dst, cursor);

    // --- CSR scan + fill (hierarchical coalesced scan; R6's 1-block scan was 127us) ---
    const int nsb = (N_NODES + 255) / 256;  // 196
    scan_block_kernel<<<nsb, 256, 0, stream>>>(cursor, rowptr, bsums, N_NODES);
    scan_sums_kernel<<<1, 256, 0, stream>>>(bsums, nsb);
    add_off_kernel<<<nsb, 256, 0, stream>>>(rowptr, bsums, cursor, N_NODES, N_EDGES);
    fill_kernel<<<(N_EDGES + 255) / 256, 256, 0, stream>>>(src, dst, cursor, esrc, N_EDGES);

    const int aggGrid = (N_NODES * 32 + 255) / 256;   // 6250
    const int gemmGrid = (N_NODES + 31) / 32;         // 1563

    // layer 0: x -> x (in place, ReLU)
    agg_kernel<<<aggGrid, 256, 0, stream>>>(xhi, rowptr, esrc, aghi, aglo, N_NODES);
    gemm_planes<128, true, true><<<gemmGrid, 256, 0, stream>>>(
        aghi, aglo, xhi, xlo, Wl0p, Wr0p, b0, nullptr, xhi, xlo, N_NODES);
    // layer 1: x -> x (in place, ReLU)
    agg_kernel<<<aggGrid, 256, 0, stream>>>(xhi, rowptr, esrc, aghi, aglo, N_NODES);
    gemm_planes<128, true, true><<<gemmGrid, 256, 0, stream>>>(
        aghi, aglo, xhi, xlo, Wl1p, Wr1p, b1, nullptr, xhi, xlo, N_NODES);
    // layer 2: x -> out (f32, no ReLU, DOUT=64)
    agg_kernel<<<aggGrid, 256, 0, stream>>>(xhi, rowptr, esrc, aghi, aglo, N_NODES);
    gemm_planes<64, false, false><<<gemmGrid, 256, 0, stream>>>(
        aghi, aglo, xhi, xlo, Wl2p, Wr2p, b2, outp, nullptr, nullptr, N_NODES);
}

// Round 8
// 326.954 us; speedup vs baseline: 1.4007x; 1.0499x over previous
//
#include <hip/hip_runtime.h>

#define N_NODES 50000
#define N_EDGES 800000
#define NBUCK 196   // dst>>8 -> 0..195

typedef __attribute__((ext_vector_type(8))) short short8;
typedef __attribute__((ext_vector_type(4))) float f32x4;
typedef __attribute__((ext_vector_type(4))) unsigned short ushort4v;
typedef __attribute__((ext_vector_type(8))) unsigned short ushort8v;

// ---------------- split-bf16 helpers ----------------
// f32 = hi(bf16) + lo(bf16) + O(2^-33). GEMM uses Ahi*Bhi + Ahi*Blo + Alo*Bhi.

__device__ inline void split_bf16(float f, unsigned short& hi, unsigned short& lo) {
    union { float f; unsigned u; } a; a.f = f;
    unsigned r = (a.u + 0x7fffu + ((a.u >> 16) & 1u)) >> 16;  // RNE to bf16
    hi = (unsigned short)r;
    union { unsigned u; float f; } b; b.u = r << 16;
    union { float f; unsigned u; } c; c.f = f - b.f;
    unsigned r2 = (c.u + 0x7fffu + ((c.u >> 16) & 1u)) >> 16;
    lo = (unsigned short)r2;
}

__device__ inline float bf2f(unsigned short u) {
    union { unsigned u; float f; } a; a.u = (unsigned)u << 16; return a.f;
}

// ---------------- prep: pack(W) + split(x) + count(dst)+bucket-hist ----------------
// blocks [0,320): pack 6 weight mats into B-fragment hi/lo planes.
// blocks [320,6570): split x into hi/lo bf16 planes.
// blocks [6570,6961): count edges per dst + per 256-node bucket (2048 edges/block).

__global__ void prep_kernel(const float* __restrict__ W0, const float* __restrict__ W1,
                            const float* __restrict__ W2, const float* __restrict__ W3,
                            const float* __restrict__ W4, const float* __restrict__ W5,
                            unsigned short* __restrict__ wout,
                            const float* __restrict__ x, unsigned short* __restrict__ xhi,
                            unsigned short* __restrict__ xlo,
                            const int* __restrict__ dst, int* __restrict__ cnt,
                            int* __restrict__ bucketCnt) {
    __shared__ int lhist[NBUCK];
    if (blockIdx.x < 320) {
        int t = blockIdx.x * 256 + threadIdx.x;  // 0..81919
        const float* W; int D, local, half; size_t base;
        if (t < 65536) {
            int mat = t >> 14; local = t & 16383; D = 128; half = 16384;
            base = (size_t)mat * 32768;
            W = mat == 0 ? W0 : mat == 1 ? W1 : mat == 2 ? W2 : W3;
        } else {
            int m = (t - 65536) >> 13; local = (t - 65536) & 8191; D = 64; half = 8192;
            base = 131072 + (size_t)m * 16384;
            W = m == 0 ? W4 : W5;
        }
        int j = local & 7, lane = (local >> 3) & 63, ks = (local >> 9) & 3, ct = local >> 11;
        int k = ks * 32 + ((lane >> 4) << 3) + j;
        int n = (ct << 4) + (lane & 15);
        unsigned short hi, lo;
        split_bf16(W[k * D + n], hi, lo);
        wout[base + local] = hi;
        wout[base + half + local] = lo;
    } else if (blockIdx.x < 6570) {
        int t = (blockIdx.x - 320) * 256 + threadIdx.x;  // one float4 per thread
        if (t >= N_NODES * 32) return;
        float4 v = *(const float4*)(x + (size_t)t * 4);
        float vv[4] = {v.x, v.y, v.z, v.w};
        ushort4v h, l;
#pragma unroll
        for (int j = 0; j < 4; ++j) {
            unsigned short a, b;
            split_bf16(vv[j], a, b);
            h[j] = a; l[j] = b;
        }
        *(ushort4v*)(xhi + (size_t)t * 4) = h;
        *(ushort4v*)(xlo + (size_t)t * 4) = l;
    } else {
        int base = (blockIdx.x - 6570) * 2048;
        if (threadIdx.x < NBUCK) lhist[threadIdx.x] = 0;
        __syncthreads();
#pragma unroll
        for (int i = 0; i < 8; ++i) {
            int e = base + i * 256 + threadIdx.x;
            if (e < N_EDGES) {
                int d = dst[e];
                atomicAdd(&cnt[d], 1);
                atomicAdd(&lhist[d >> 8], 1);
            }
        }
        __syncthreads();
        if (threadIdx.x < NBUCK) atomicAdd(&bucketCnt[threadIdx.x], lhist[threadIdx.x]);
    }
}

// ---------------- CSR scans (hierarchical, coalesced) ----------------

__global__ void scan_block_kernel(const int* __restrict__ cnt, int* __restrict__ rowptr,
                                  int* __restrict__ bsums, int n) {
    __shared__ int s[256];
    int tid = threadIdx.x;
    int i = blockIdx.x * 256 + tid;
    int v = (i < n) ? cnt[i] : 0;
    s[tid] = v;
    __syncthreads();
    for (int off = 1; off < 256; off <<= 1) {
        int t = (tid >= off) ? s[tid - off] : 0;
        __syncthreads();
        s[tid] += t;
        __syncthreads();
    }
    if (i < n) rowptr[i] = s[tid] - v;   // exclusive
    if (tid == 255) bsums[blockIdx.x] = s[255];
}

// scans bsums (196) AND bucketCnt (196 -> bucketBase/bucketCur) in one block
__global__ void scan_sums_kernel(int* bsums, int nb, const int* __restrict__ bucketCnt,
                                 int* __restrict__ bucketBase, int* __restrict__ bucketCur,
                                 int E) {
    __shared__ int s[256];
    int tid = threadIdx.x;
    int v = (tid < nb) ? bsums[tid] : 0;
    s[tid] = v;
    __syncthreads();
    for (int off = 1; off < 256; off <<= 1) {
        int t = (tid >= off) ? s[tid - off] : 0;
        __syncthreads();
        s[tid] += t;
        __syncthreads();
    }
    if (tid < nb) bsums[tid] = s[tid] - v;  // exclusive, in place
    __syncthreads();
    int v2 = (tid < NBUCK) ? bucketCnt[tid] : 0;
    s[tid] = v2;
    __syncthreads();
    for (int off = 1; off < 256; off <<= 1) {
        int t = (tid >= off) ? s[tid - off] : 0;
        __syncthreads();
        s[tid] += t;
        __syncthreads();
    }
    if (tid < NBUCK) { int b = s[tid] - v2; bucketBase[tid] = b; bucketCur[tid] = b; }
    if (tid == 0) bucketBase[NBUCK] = E;
}

__global__ void add_off_kernel(int* __restrict__ rowptr, const int* __restrict__ bsums,
                               int n, int E) {
    int i = blockIdx.x * blockDim.x + threadIdx.x;
    if (i < n) rowptr[i] += bsums[i >> 8];
    if (i == 0) rowptr[n] = E;
}

// ---------------- edge partition into 196 buckets (LDS-staged, coalesced) ----
// R7 lesson: direct 4B random scatter = 64B line write-allocate each -> 52MB
// HBM writes for a 3.2MB array. Stage-sort 2048 edges in LDS, write runs
// coalesced. Edge packed (dst<<16)|src (both < 2^16).

__global__ __launch_bounds__(256) void partition_kernel(
    const int* __restrict__ src, const int* __restrict__ dst,
    int* __restrict__ bucketCur, unsigned int* __restrict__ ebuf, int E) {
    __shared__ int hist[NBUCK], binoff[NBUCK], bincur[NBUCK], runstart[NBUCK];
    __shared__ int scanbuf[256];
    __shared__ unsigned int sortbuf[2048];
    const int tid = threadIdx.x;
    const int base = blockIdx.x * 2048;
    if (tid < NBUCK) hist[tid] = 0;
    __syncthreads();
    int myb[8]; unsigned int myp[8];
#pragma unroll
    for (int i = 0; i < 8; ++i) {
        int e = base + i * 256 + tid;
        if (e < E) {
            int d = dst[e], s = src[e];
            myb[i] = d >> 8;
            myp[i] = ((unsigned)d << 16) | (unsigned)s;
            atomicAdd(&hist[myb[i]], 1);
        } else myb[i] = -1;
    }
    __syncthreads();
    int v = (tid < NBUCK) ? hist[tid] : 0;
    scanbuf[tid] = v;
    __syncthreads();
    for (int off = 1; off < 256; off <<= 1) {
        int t = (tid >= off) ? scanbuf[tid - off] : 0;
        __syncthreads();
        scanbuf[tid] += t;
        __syncthreads();
    }
    if (tid < NBUCK) {
        binoff[tid] = scanbuf[tid] - v;
        bincur[tid] = 0;
        runstart[tid] = atomicAdd(&bucketCur[tid], v);
    }
    __syncthreads();
#pragma unroll
    for (int i = 0; i < 8; ++i) {
        if (myb[i] >= 0) {
            int r = atomicAdd(&bincur[myb[i]], 1);
            sortbuf[binoff[myb[i]] + r] = myp[i];
        }
    }
    __syncthreads();
    int nloc = E - base; if (nloc > 2048) nloc = 2048;
#pragma unroll
    for (int i = 0; i < 8; ++i) {
        int idx = i * 256 + tid;
        if (idx < nloc) {
            unsigned int p = sortbuf[idx];
            int b = p >> 24;   // (dst>>8)
            ebuf[runstart[b] + (idx - binoff[b])] = p;
        }
    }
}

// ---------------- fine fill: bucket -> exact CSR (single-CU-local scatter) ----

__global__ __launch_bounds__(256) void fine_fill_kernel(
    const unsigned int* __restrict__ ebuf, const int* __restrict__ bucketBase,
    const int* __restrict__ rowptr, unsigned short* __restrict__ esrc, int n) {
    __shared__ int cur[256];
    const int b = blockIdx.x, tid = threadIdx.x;
    const int nbase = b << 8;
    if (nbase + tid < n) cur[tid] = rowptr[nbase + tid];
    __syncthreads();
    const int lo = bucketBase[b], hi = bucketBase[b + 1];
    for (int k = lo + tid; k < hi; k += 256) {
        unsigned int p = ebuf[k];
        int pos = atomicAdd(&cur[(p >> 16) & 255], 1);
        esrc[pos] = (unsigned short)(p & 0xFFFFu);
    }
}

// ---------------- mean aggregation (CSR gather, bf16-hi plane) ----------------
// 16 lanes per node (ushort8v = 16B/lane), 50k independent groups, 4-way
// interleaved neighbor loop -> 4 x 16B loads in flight per lane.

__global__ __launch_bounds__(256, 6) void agg_kernel(
    const unsigned short* __restrict__ Hhi, const int* __restrict__ rowptr,
    const unsigned short* __restrict__ esrc,
    unsigned short* __restrict__ Ahi, unsigned short* __restrict__ Alo, int n) {
    int g = (blockIdx.x * blockDim.x + threadIdx.x) >> 4;
    int l16 = threadIdx.x & 15;
    if (g >= n) return;
    int beg = rowptr[g], end = rowptr[g + 1];
    float a0[8] = {0,0,0,0,0,0,0,0}, a1[8] = {0,0,0,0,0,0,0,0};
    float a2[8] = {0,0,0,0,0,0,0,0}, a3[8] = {0,0,0,0,0,0,0,0};
    int k = beg;
    for (; k + 4 <= end; k += 4) {
        int e0 = esrc[k], e1 = esrc[k + 1], e2 = esrc[k + 2], e3 = esrc[k + 3];
        ushort8v v0 = *(const ushort8v*)(Hhi + (size_t)e0 * 128 + l16 * 8);
        ushort8v v1 = *(const ushort8v*)(Hhi + (size_t)e1 * 128 + l16 * 8);
        ushort8v v2 = *(const ushort8v*)(Hhi + (size_t)e2 * 128 + l16 * 8);
        ushort8v v3 = *(const ushort8v*)(Hhi + (size_t)e3 * 128 + l16 * 8);
#pragma unroll
        for (int j = 0; j < 8; ++j) {
            a0[j] += bf2f(v0[j]); a1[j] += bf2f(v1[j]);
            a2[j] += bf2f(v2[j]); a3[j] += bf2f(v3[j]);
        }
    }
    for (; k < end; ++k) {
        int e0 = esrc[k];
        ushort8v v0 = *(const ushort8v*)(Hhi + (size_t)e0 * 128 + l16 * 8);
#pragma unroll
        for (int j = 0; j < 8; ++j) a0[j] += bf2f(v0[j]);
    }
    float inv = (end > beg) ? 1.0f / (float)(end - beg) : 0.0f;
    ushort8v mh, ml;
#pragma unroll
    for (int j = 0; j < 8; ++j) {
        float m = (a0[j] + a1[j] + a2[j] + a3[j]) * inv;
        unsigned short h, l;
        split_bf16(m, h, l);
        mh[j] = h; ml[j] = l;
    }
    *(ushort8v*)(Ahi + (size_t)g * 128 + l16 * 8) = mh;
    *(ushort8v*)(Alo + (size_t)g * 128 + l16 * 8) = ml;
}

// ---------------- dual GEMM via MFMA (plane inputs, verbatim staging) --------
// out = A1@W1 + A2@W2 + b (opt ReLU). BM=32, 256 thr = 4 waves.
// In-place safe: block stages only its own 32 rows before writing them.

template <int DOUT, bool RELU, bool SPLIT_OUT>
__global__ __launch_bounds__(256, 4) void gemm_planes(
    const unsigned short* __restrict__ A1hi, const unsigned short* __restrict__ A1lo,
    const unsigned short* __restrict__ A2hi, const unsigned short* __restrict__ A2lo,
    const unsigned short* __restrict__ B1p, const unsigned short* __restrict__ B2p,
    const float* __restrict__ bias, float* __restrict__ outf,
    unsigned short* __restrict__ outhi, unsigned short* __restrict__ outlo, int M) {
    constexpr int K = 128, BM = 32, KS = 4, CT = DOUT / 16, CPW = CT / 4;
    constexpr int PITCH = K + 8;
    constexpr int HALF = CT * KS * 512;
    __shared__ unsigned short As[2][2][BM * PITCH];  // [mat][hi/lo][row*PITCH+k]

    const int tid = threadIdx.x;
    const int r0 = blockIdx.x * BM;

    const unsigned short* __restrict__ srcs[4] = {A1hi, A1lo, A2hi, A2lo};
#pragma unroll
    for (int s = 0; s < 4; ++s) {
#pragma unroll
        for (int c = 0; c < 2; ++c) {
            int chunk = tid + c * 256;
            int row = chunk >> 4;
            int c8 = (chunk & 15) * 8;
            int grow = r0 + row; if (grow >= M) grow = M - 1;
            *(ushort8v*)(&As[s >> 1][s & 1][row * PITCH + c8]) =
                *(const ushort8v*)(srcs[s] + (size_t)grow * K + c8);
        }
    }
    __syncthreads();

    const int wave = tid >> 6, lane = tid & 63;
    const int rl = lane & 15, quad = lane >> 4;

    f32x4 acc[2][CPW];
#pragma unroll
    for (int c = 0; c < CPW; ++c) {
        float bv = bias[(wave * CPW + c) * 16 + rl];
        acc[0][c] = (f32x4){bv, bv, bv, bv};
        acc[1][c] = acc[0][c];
    }

#pragma unroll
    for (int mat = 0; mat < 2; ++mat) {
        const unsigned short* __restrict__ Bp = mat ? B2p : B1p;
#pragma unroll
        for (int ks = 0; ks < KS; ++ks) {
            short8 a[2][2];
#pragma unroll
            for (int rt = 0; rt < 2; ++rt)
#pragma unroll
                for (int p = 0; p < 2; ++p)
                    a[rt][p] = *(const short8*)(&As[mat][p][(rt * 16 + rl) * PITCH + ks * 32 + quad * 8]);
            short8 b[CPW][2];
#pragma unroll
            for (int c = 0; c < CPW; ++c)
#pragma unroll
                for (int p = 0; p < 2; ++p)
                    b[c][p] = *(const short8*)(Bp + p * HALF +
                                               (((wave * CPW + c) * KS + ks) * 64 + lane) * 8);
#pragma unroll
            for (int rt = 0; rt < 2; ++rt)
#pragma unroll
                for (int c = 0; c < CPW; ++c) {
                    acc[rt][c] = __builtin_amdgcn_mfma_f32_16x16x32_bf16(a[rt][0], b[c][0], acc[rt][c], 0, 0, 0);
                    acc[rt][c] = __builtin_amdgcn_mfma_f32_16x16x32_bf16(a[rt][0], b[c][1], acc[rt][c], 0, 0, 0);
                    acc[rt][c] = __builtin_amdgcn_mfma_f32_16x16x32_bf16(a[rt][1], b[c][0], acc[rt][c], 0, 0, 0);
                }
        }
    }

#pragma unroll
    for (int rt = 0; rt < 2; ++rt)
#pragma unroll
        for (int c = 0; c < CPW; ++c) {
            int col = (wave * CPW + c) * 16 + rl;
            int rowb = r0 + rt * 16 + quad * 4;
#pragma unroll
            for (int r = 0; r < 4; ++r) {
                int rr = rowb + r;
                if (rr < M) {
                    float vv = acc[rt][c][r];
                    if (RELU) vv = fmaxf(vv, 0.f);
                    if (SPLIT_OUT) {
                        unsigned short h, l;
                        split_bf16(vv, h, l);
                        outhi[(size_t)rr * DOUT + col] = h;
                        outlo[(size_t)rr * DOUT + col] = l;
                    } else {
                        outf[(size_t)rr * DOUT + col] = vv;
                    }
                }
            }
        }
}

// ---------------- launch ----------------

extern "C" void kernel_launch(void* const* d_in, const int* in_sizes, int n_in,
                              void* d_out, int out_size, void* d_ws, size_t ws_size,
                              hipStream_t stream) {
    const float* x   = (const float*)d_in[0];
    const int* eidx  = (const int*)d_in[1];
    const int* src   = eidx;             // edge_index[0]
    const int* dst   = eidx + N_EDGES;   // edge_index[1]
    const float* Wl0 = (const float*)d_in[2];
    const float* b0  = (const float*)d_in[3];
    const float* Wr0 = (const float*)d_in[4];
    const float* Wl1 = (const float*)d_in[5];
    const float* b1  = (const float*)d_in[6];
    const float* Wr1 = (const float*)d_in[7];
    const float* Wl2 = (const float*)d_in[8];
    const float* b2  = (const float*)d_in[9];
    const float* Wr2 = (const float*)d_in[10];
    float* outp = (float*)d_out;

    // workspace (~53.5 MB)
    unsigned short* xhi  = (unsigned short*)d_ws;           // N*128 each
    unsigned short* xlo  = xhi + (size_t)N_NODES * 128;
    unsigned short* aghi = xlo + (size_t)N_NODES * 128;
    unsigned short* aglo = aghi + (size_t)N_NODES * 128;
    unsigned int* ebuf = (unsigned int*)aghi;               // ALIAS: consumed before agg writes
    int* rowptr    = (int*)(aglo + (size_t)N_NODES * 128);  // 50016
    int* nodecnt   = rowptr + 50016;                        // 50000  } contiguous
    int* bucketCnt = nodecnt + N_NODES;                     // 256    } memset zone
    int* bucketBase= bucketCnt + 256;                       // 256 (197 used)
    int* bucketCur = bucketBase + 256;                      // 256
    int* bsums     = bucketCur + 256;                       // 256
    unsigned short* esrc  = (unsigned short*)(bsums + 256); // E ushort = 1.6MB
    unsigned short* packw = esrc + N_EDGES;                 // 163840 bf16 (16B-aligned)
    unsigned short* Wl0p = packw;
    unsigned short* Wr0p = packw + 32768;
    unsigned short* Wl1p = packw + 65536;
    unsigned short* Wr1p = packw + 98304;
    unsigned short* Wl2p = packw + 131072;
    unsigned short* Wr2p = packw + 147456;

    // --- prep (pack W + split x + count node/bucket) after zeroing counters ---
    hipMemsetAsync(nodecnt, 0, (N_NODES + 256) * sizeof(int), stream);
    prep_kernel<<<6961, 256, 0, stream>>>(Wl0, Wr0, Wl1, Wr1, Wl2, Wr2, packw,
                                          x, xhi, xlo, dst, nodecnt, bucketCnt);

    // --- CSR: hierarchical scan + bucketed partition + fine fill ---
    const int nsb = (N_NODES + 255) / 256;  // 196
    scan_block_kernel<<<nsb, 256, 0, stream>>>(nodecnt, rowptr, bsums, N_NODES);
    scan_sums_kernel<<<1, 256, 0, stream>>>(bsums, nsb, bucketCnt, bucketBase, bucketCur, N_EDGES);
    add_off_kernel<<<nsb, 256, 0, stream>>>(rowptr, bsums, N_NODES, N_EDGES);
    partition_kernel<<<(N_EDGES + 2047) / 2048, 256, 0, stream>>>(src, dst, bucketCur, ebuf, N_EDGES);
    fine_fill_kernel<<<NBUCK, 256, 0, stream>>>(ebuf, bucketBase, rowptr, esrc, N_NODES);

    const int aggGrid = (N_NODES * 16 + 255) / 256;   // 3125
    const int gemmGrid = (N_NODES + 31) / 32;         // 1563

    // layer 0: x -> x (in place, ReLU)
    agg_kernel<<<aggGrid, 256, 0, stream>>>(xhi, rowptr, esrc, aghi, aglo, N_NODES);
    gemm_planes<128, true, true><<<gemmGrid, 256, 0, stream>>>(
        aghi, aglo, xhi, xlo, Wl0p, Wr0p, b0, nullptr, xhi, xlo, N_NODES);
    // layer 1: x -> x (in place, ReLU)
    agg_kernel<<<aggGrid, 256, 0, stream>>>(xhi, rowptr, esrc, aghi, aglo, N_NODES);
    gemm_planes<128, true, true><<<gemmGrid, 256, 0, stream>>>(
        aghi, aglo, xhi, xlo, Wl1p, Wr1p, b1, nullptr, xhi, xlo, N_NODES);
    // layer 2: x -> out (f32, no ReLU, DOUT=64)
    agg_kernel<<<aggGrid, 256, 0, stream>>>(xhi, rowptr, esrc, aghi, aglo, N_NODES);
    gemm_planes<64, false, false><<<gemmGrid, 256, 0, stream>>>(
        aghi, aglo, xhi, xlo, Wl2p, Wr2p, b2, outp, nullptr, nullptr, N_NODES);
}

// Round 10
// 295.397 us; speedup vs baseline: 1.5504x; 1.1068x over previous
//
#include <hip/hip_runtime.h>

#define N_NODES 50000
#define N_EDGES 800000
#define NBUCK 196    // dst>>8 -> 0..195
#define NHIST 98     // histogram blocks (8192 edges each)

typedef __attribute__((ext_vector_type(8))) short short8;
typedef __attribute__((ext_vector_type(4))) float f32x4;
typedef __attribute__((ext_vector_type(4))) unsigned short ushort4v;
typedef __attribute__((ext_vector_type(8))) unsigned short ushort8v;

// ---------------- split-bf16 helpers ----------------
// f32 = hi(bf16) + lo(bf16) + O(2^-33). GEMM uses Ahi*Bhi + Ahi*Blo + Alo*Bhi.

__device__ inline void split_bf16(float f, unsigned short& hi, unsigned short& lo) {
    union { float f; unsigned u; } a; a.f = f;
    unsigned r = (a.u + 0x7fffu + ((a.u >> 16) & 1u)) >> 16;  // RNE to bf16
    hi = (unsigned short)r;
    union { unsigned u; float f; } b; b.u = r << 16;
    union { float f; unsigned u; } c; c.f = f - b.f;
    unsigned r2 = (c.u + 0x7fffu + ((c.u >> 16) & 1u)) >> 16;
    lo = (unsigned short)r2;
}

__device__ inline float bf2f(unsigned short u) {
    union { unsigned u; float f; } a; a.u = (unsigned)u << 16; return a.f;
}

// ---------------- prep: pack(W) + split(x) + bucket histogram ----------------
// blocks [0,320): pack 6 weight mats into B-fragment hi/lo planes.
// blocks [320,6570): split x into hi/lo bf16 planes.
// blocks [6570,6668): bucket histogram, 8192 edges/block, per-block LDS hist
//   written PLAIN to blkhist[blk][196] (no global atomics, no pre-zeroing).

__global__ void prep_kernel(const float* __restrict__ W0, const float* __restrict__ W1,
                            const float* __restrict__ W2, const float* __restrict__ W3,
                            const float* __restrict__ W4, const float* __restrict__ W5,
                            unsigned short* __restrict__ wout,
                            const float* __restrict__ x, unsigned short* __restrict__ xhi,
                            unsigned short* __restrict__ xlo,
                            const int* __restrict__ dst, int* __restrict__ blkhist) {
    __shared__ int lhist[NBUCK];
    if (blockIdx.x < 320) {
        int t = blockIdx.x * 256 + threadIdx.x;  // 0..81919
        const float* W; int D, local, half; size_t base;
        if (t < 65536) {
            int mat = t >> 14; local = t & 16383; D = 128; half = 16384;
            base = (size_t)mat * 32768;
            W = mat == 0 ? W0 : mat == 1 ? W1 : mat == 2 ? W2 : W3;
        } else {
            int m = (t - 65536) >> 13; local = (t - 65536) & 8191; D = 64; half = 8192;
            base = 131072 + (size_t)m * 16384;
            W = m == 0 ? W4 : W5;
        }
        int j = local & 7, lane = (local >> 3) & 63, ks = (local >> 9) & 3, ct = local >> 11;
        int k = ks * 32 + ((lane >> 4) << 3) + j;
        int n = (ct << 4) + (lane & 15);
        unsigned short hi, lo;
        split_bf16(W[k * D + n], hi, lo);
        wout[base + local] = hi;
        wout[base + half + local] = lo;
    } else if (blockIdx.x < 6570) {
        int t = (blockIdx.x - 320) * 256 + threadIdx.x;  // one float4 per thread
        if (t >= N_NODES * 32) return;
        float4 v = *(const float4*)(x + (size_t)t * 4);
        float vv[4] = {v.x, v.y, v.z, v.w};
        ushort4v h, l;
#pragma unroll
        for (int j = 0; j < 4; ++j) {
            unsigned short a, b;
            split_bf16(vv[j], a, b);
            h[j] = a; l[j] = b;
        }
        *(ushort4v*)(xhi + (size_t)t * 4) = h;
        *(ushort4v*)(xlo + (size_t)t * 4) = l;
    } else {
        const int hb = blockIdx.x - 6570;
        const int base = hb * 8192;
        if (threadIdx.x < NBUCK) lhist[threadIdx.x] = 0;
        __syncthreads();
#pragma unroll
        for (int i = 0; i < 32; ++i) {
            int e = base + i * 256 + threadIdx.x;
            if (e < N_EDGES) atomicAdd(&lhist[dst[e] >> 8], 1);
        }
        __syncthreads();
        if (threadIdx.x < NBUCK) blkhist[hb * NBUCK + threadIdx.x] = lhist[threadIdx.x];
    }
}

// ---------------- bucket scan (1 block): blkhist -> bucketBase/bucketCur -----

__global__ void scan_sums_kernel(const int* __restrict__ blkhist,
                                 int* __restrict__ bucketBase, int* __restrict__ bucketCur,
                                 int* __restrict__ rowptr) {
    __shared__ int s[256];
    int tid = threadIdx.x;
    int v = 0;
    if (tid < NBUCK)
        for (int h = 0; h < NHIST; ++h) v += blkhist[h * NBUCK + tid];
    s[tid] = v;
    __syncthreads();
    for (int off = 1; off < 256; off <<= 1) {
        int t = (tid >= off) ? s[tid - off] : 0;
        __syncthreads();
        s[tid] += t;
        __syncthreads();
    }
    if (tid < NBUCK) {
        int b = s[tid] - v;
        bucketBase[tid] = b;
        bucketCur[tid] = b;
    }
    if (tid == 0) { bucketBase[NBUCK] = N_EDGES; rowptr[N_NODES] = N_EDGES; }
}

// ---------------- edge partition into 196 buckets (LDS-staged, coalesced) ----
// Direct 4B random scatter = 64B-line write-allocate each (52MB for 3.2MB, R7).
// Stage-sort 2048 edges in LDS, write runs coalesced. Packed (dst<<16)|src.

__global__ __launch_bounds__(256) void partition_kernel(
    const int* __restrict__ src, const int* __restrict__ dst,
    int* __restrict__ bucketCur, unsigned int* __restrict__ ebuf, int E) {
    __shared__ int hist[NBUCK], binoff[NBUCK], bincur[NBUCK], runstart[NBUCK];
    __shared__ int scanbuf[256];
    __shared__ unsigned int sortbuf[2048];
    const int tid = threadIdx.x;
    const int base = blockIdx.x * 2048;
    if (tid < NBUCK) hist[tid] = 0;
    __syncthreads();
    int myb[8]; unsigned int myp[8];
#pragma unroll
    for (int i = 0; i < 8; ++i) {
        int e = base + i * 256 + tid;
        if (e < E) {
            int d = dst[e], s = src[e];
            myb[i] = d >> 8;
            myp[i] = ((unsigned)d << 16) | (unsigned)s;
            atomicAdd(&hist[myb[i]], 1);
        } else myb[i] = -1;
    }
    __syncthreads();
    int v = (tid < NBUCK) ? hist[tid] : 0;
    scanbuf[tid] = v;
    __syncthreads();
    for (int off = 1; off < 256; off <<= 1) {
        int t = (tid >= off) ? scanbuf[tid - off] : 0;
        __syncthreads();
        scanbuf[tid] += t;
        __syncthreads();
    }
    if (tid < NBUCK) {
        binoff[tid] = scanbuf[tid] - v;
        bincur[tid] = 0;
        runstart[tid] = atomicAdd(&bucketCur[tid], v);
    }
    __syncthreads();
#pragma unroll
    for (int i = 0; i < 8; ++i) {
        if (myb[i] >= 0) {
            int r = atomicAdd(&bincur[myb[i]], 1);
            sortbuf[binoff[myb[i]] + r] = myp[i];
        }
    }
    __syncthreads();
    int nloc = E - base; if (nloc > 2048) nloc = 2048;
#pragma unroll
    for (int i = 0; i < 8; ++i) {
        int idx = i * 256 + tid;
        if (idx < nloc) {
            unsigned int p = sortbuf[idx];
            int b = p >> 24;   // dst>>8
            ebuf[runstart[b] + (idx - binoff[b])] = p;
        }
    }
}

// ---------------- fine fill: per bucket, derive rowptr + scatter esrc ---------
// Per-node counts within the bucket are complete (nodes partitioned by dst>>8),
// so rowptr[node] = bucketBase[b] + LDS-scan of in-bucket counts. No global
// count pass needed at all.

__global__ __launch_bounds__(256) void fine_fill_kernel(
    const unsigned int* __restrict__ ebuf, const int* __restrict__ bucketBase,
    int* __restrict__ rowptr, unsigned short* __restrict__ esrc, int n) {
    __shared__ int cnt[256], scanbuf[256], cur[256];
    const int b = blockIdx.x, tid = threadIdx.x;
    const int nbase = b << 8;
    cnt[tid] = 0;
    __syncthreads();
    const int lo = bucketBase[b], hi = bucketBase[b + 1];
    for (int k = lo + tid; k < hi; k += 256)
        atomicAdd(&cnt[(ebuf[k] >> 16) & 255], 1);
    __syncthreads();
    int v = cnt[tid];
    scanbuf[tid] = v;
    __syncthreads();
    for (int off = 1; off < 256; off <<= 1) {
        int t = (tid >= off) ? scanbuf[tid - off] : 0;
        __syncthreads();
        scanbuf[tid] += t;
        __syncthreads();
    }
    int start = lo + scanbuf[tid] - v;   // exclusive
    if (nbase + tid < n) rowptr[nbase + tid] = start;
    cur[tid] = start;
    __syncthreads();
    for (int k = lo + tid; k < hi; k += 256) {
        unsigned int p = ebuf[k];
        int pos = atomicAdd(&cur[(p >> 16) & 255], 1);
        esrc[pos] = (unsigned short)(p & 0xFFFFu);
    }
}

// ---------------- mean aggregation (CSR gather, bf16-hi plane) ----------------
// 16 lanes per node (ushort8v = 16B/lane), 50k independent groups, 4-way
// interleaved neighbor loop -> 4 x 16B loads in flight per lane.

__global__ __launch_bounds__(256, 6) void agg_kernel(
    const unsigned short* __restrict__ Hhi, const int* __restrict__ rowptr,
    const unsigned short* __restrict__ esrc,
    unsigned short* __restrict__ Ahi, unsigned short* __restrict__ Alo, int n) {
    int g = (blockIdx.x * blockDim.x + threadIdx.x) >> 4;
    int l16 = threadIdx.x & 15;
    if (g >= n) return;
    int beg = rowptr[g], end = rowptr[g + 1];
    float a0[8] = {0,0,0,0,0,0,0,0}, a1[8] = {0,0,0,0,0,0,0,0};
    float a2[8] = {0,0,0,0,0,0,0,0}, a3[8] = {0,0,0,0,0,0,0,0};
    int k = beg;
    for (; k + 4 <= end; k += 4) {
        int e0 = esrc[k], e1 = esrc[k + 1], e2 = esrc[k + 2], e3 = esrc[k + 3];
        ushort8v v0 = *(const ushort8v*)(Hhi + (size_t)e0 * 128 + l16 * 8);
        ushort8v v1 = *(const ushort8v*)(Hhi + (size_t)e1 * 128 + l16 * 8);
        ushort8v v2 = *(const ushort8v*)(Hhi + (size_t)e2 * 128 + l16 * 8);
        ushort8v v3 = *(const ushort8v*)(Hhi + (size_t)e3 * 128 + l16 * 8);
#pragma unroll
        for (int j = 0; j < 8; ++j) {
            a0[j] += bf2f(v0[j]); a1[j] += bf2f(v1[j]);
            a2[j] += bf2f(v2[j]); a3[j] += bf2f(v3[j]);
        }
    }
    for (; k < end; ++k) {
        int e0 = esrc[k];
        ushort8v v0 = *(const ushort8v*)(Hhi + (size_t)e0 * 128 + l16 * 8);
#pragma unroll
        for (int j = 0; j < 8; ++j) a0[j] += bf2f(v0[j]);
    }
    float inv = (end > beg) ? 1.0f / (float)(end - beg) : 0.0f;
    ushort8v mh, ml;
#pragma unroll
    for (int j = 0; j < 8; ++j) {
        float m = (a0[j] + a1[j] + a2[j] + a3[j]) * inv;
        unsigned short h, l;
        split_bf16(m, h, l);
        mh[j] = h; ml[j] = l;
    }
    *(ushort8v*)(Ahi + (size_t)g * 128 + l16 * 8) = mh;
    *(ushort8v*)(Alo + (size_t)g * 128 + l16 * 8) = ml;
}

// ---------------- dual GEMM via MFMA (plane inputs, verbatim staging) --------
// out = A1@W1 + A2@W2 + b (opt ReLU). BM=32, 256 thr = 4 waves.
// In-place safe: block stages only its own 32 rows before writing them.

template <int DOUT, bool RELU, bool SPLIT_OUT>
__global__ __launch_bounds__(256, 4) void gemm_planes(
    const unsigned short* __restrict__ A1hi, const unsigned short* __restrict__ A1lo,
    const unsigned short* __restrict__ A2hi, const unsigned short* __restrict__ A2lo,
    const unsigned short* __restrict__ B1p, const unsigned short* __restrict__ B2p,
    const float* __restrict__ bias, float* __restrict__ outf,
    unsigned short* __restrict__ outhi, unsigned short* __restrict__ outlo, int M) {
    constexpr int K = 128, BM = 32, KS = 4, CT = DOUT / 16, CPW = CT / 4;
    constexpr int PITCH = K + 8;
    constexpr int HALF = CT * KS * 512;
    __shared__ unsigned short As[2][2][BM * PITCH];  // [mat][hi/lo][row*PITCH+k]

    const int tid = threadIdx.x;
    const int r0 = blockIdx.x * BM;

    const unsigned short* __restrict__ srcs[4] = {A1hi, A1lo, A2hi, A2lo};
#pragma unroll
    for (int s = 0; s < 4; ++s) {
#pragma unroll
        for (int c = 0; c < 2; ++c) {
            int chunk = tid + c * 256;
            int row = chunk >> 4;
            int c8 = (chunk & 15) * 8;
            int grow = r0 + row; if (grow >= M) grow = M - 1;
            *(ushort8v*)(&As[s >> 1][s & 1][row * PITCH + c8]) =
                *(const ushort8v*)(srcs[s] + (size_t)grow * K + c8);
        }
    }
    __syncthreads();

    const int wave = tid >> 6, lane = tid & 63;
    const int rl = lane & 15, quad = lane >> 4;

    f32x4 acc[2][CPW];
#pragma unroll
    for (int c = 0; c < CPW; ++c) {
        float bv = bias[(wave * CPW + c) * 16 + rl];
        acc[0][c] = (f32x4){bv, bv, bv, bv};
        acc[1][c] = acc[0][c];
    }

#pragma unroll
    for (int mat = 0; mat < 2; ++mat) {
        const unsigned short* __restrict__ Bp = mat ? B2p : B1p;
#pragma unroll
        for (int ks = 0; ks < KS; ++ks) {
            short8 a[2][2];
#pragma unroll
            for (int rt = 0; rt < 2; ++rt)
#pragma unroll
                for (int p = 0; p < 2; ++p)
                    a[rt][p] = *(const short8*)(&As[mat][p][(rt * 16 + rl) * PITCH + ks * 32 + quad * 8]);
            short8 b[CPW][2];
#pragma unroll
            for (int c = 0; c < CPW; ++c)
#pragma unroll
                for (int p = 0; p < 2; ++p)
                    b[c][p] = *(const short8*)(Bp + p * HALF +
                                               (((wave * CPW + c) * KS + ks) * 64 + lane) * 8);
#pragma unroll
            for (int rt = 0; rt < 2; ++rt)
#pragma unroll
                for (int c = 0; c < CPW; ++c) {
                    acc[rt][c] = __builtin_amdgcn_mfma_f32_16x16x32_bf16(a[rt][0], b[c][0], acc[rt][c], 0, 0, 0);
                    acc[rt][c] = __builtin_amdgcn_mfma_f32_16x16x32_bf16(a[rt][0], b[c][1], acc[rt][c], 0, 0, 0);
                    acc[rt][c] = __builtin_amdgcn_mfma_f32_16x16x32_bf16(a[rt][1], b[c][0], acc[rt][c], 0, 0, 0);
                }
        }
    }

#pragma unroll
    for (int rt = 0; rt < 2; ++rt)
#pragma unroll
        for (int c = 0; c < CPW; ++c) {
            int col = (wave * CPW + c) * 16 + rl;
            int rowb = r0 + rt * 16 + quad * 4;
#pragma unroll
            for (int r = 0; r < 4; ++r) {
                int rr = rowb + r;
                if (rr < M) {
                    float vv = acc[rt][c][r];
                    if (RELU) vv = fmaxf(vv, 0.f);
                    if (SPLIT_OUT) {
                        unsigned short h, l;
                        split_bf16(vv, h, l);
                        outhi[(size_t)rr * DOUT + col] = h;
                        outlo[(size_t)rr * DOUT + col] = l;
                    } else {
                        outf[(size_t)rr * DOUT + col] = vv;
                    }
                }
            }
        }
}

// ---------------- launch ----------------

extern "C" void kernel_launch(void* const* d_in, const int* in_sizes, int n_in,
                              void* d_out, int out_size, void* d_ws, size_t ws_size,
                              hipStream_t stream) {
    const float* x   = (const float*)d_in[0];
    const int* eidx  = (const int*)d_in[1];
    const int* src   = eidx;             // edge_index[0]
    const int* dst   = eidx + N_EDGES;   // edge_index[1]
    const float* Wl0 = (const float*)d_in[2];
    const float* b0  = (const float*)d_in[3];
    const float* Wr0 = (const float*)d_in[4];
    const float* Wl1 = (const float*)d_in[5];
    const float* b1  = (const float*)d_in[6];
    const float* Wr1 = (const float*)d_in[7];
    const float* Wl2 = (const float*)d_in[8];
    const float* b2  = (const float*)d_in[9];
    const float* Wr2 = (const float*)d_in[10];
    float* outp = (float*)d_out;

    // workspace (~54 MB)
    unsigned short* xhi  = (unsigned short*)d_ws;           // N*128 each
    unsigned short* xlo  = xhi + (size_t)N_NODES * 128;
    unsigned short* aghi = xlo + (size_t)N_NODES * 128;
    unsigned short* aglo = aghi + (size_t)N_NODES * 128;
    unsigned int* ebuf = (unsigned int*)aghi;               // ALIAS: consumed before agg writes
    int* rowptr    = (int*)(aglo + (size_t)N_NODES * 128);  // 50016
    int* blkhist   = rowptr + 50016;                        // 98*196 = 19208
    int* bucketBase= blkhist + 19208;                       // 256 (197 used)
    int* bucketCur = bucketBase + 256;                      // 256
    unsigned short* esrc  = (unsigned short*)(bucketCur + 256); // E ushort = 1.6MB
    unsigned short* packw = esrc + N_EDGES;                 // 163840 bf16 (16B-aligned)
    unsigned short* Wl0p = packw;
    unsigned short* Wr0p = packw + 32768;
    unsigned short* Wl1p = packw + 65536;
    unsigned short* Wr1p = packw + 98304;
    unsigned short* Wl2p = packw + 131072;
    unsigned short* Wr2p = packw + 147456;

    // --- prep (pack W + split x + per-block bucket hist; no atomics to global) ---
    prep_kernel<<<6668, 256, 0, stream>>>(Wl0, Wr0, Wl1, Wr1, Wl2, Wr2, packw,
                                          x, xhi, xlo, dst, blkhist);
    // --- bucket scan (1 block) -> bucketBase/bucketCur, rowptr[N]=E ---
    scan_sums_kernel<<<1, 256, 0, stream>>>(blkhist, bucketBase, bucketCur, rowptr);
    // --- partition edges into buckets (coalesced), then per-bucket CSR ---
    partition_kernel<<<(N_EDGES + 2047) / 2048, 256, 0, stream>>>(src, dst, bucketCur, ebuf, N_EDGES);
    fine_fill_kernel<<<NBUCK, 256, 0, stream>>>(ebuf, bucketBase, rowptr, esrc, N_NODES);

    const int aggGrid = (N_NODES * 16 + 255) / 256;   // 3125
    const int gemmGrid = (N_NODES + 31) / 32;         // 1563

    // layer 0: x -> x (in place, ReLU)
    agg_kernel<<<aggGrid, 256, 0, stream>>>(xhi, rowptr, esrc, aghi, aglo, N_NODES);
    gemm_planes<128, true, true><<<gemmGrid, 256, 0, stream>>>(
        aghi, aglo, xhi, xlo, Wl0p, Wr0p, b0, nullptr, xhi, xlo, N_NODES);
    // layer 1: x -> x (in place, ReLU)
    agg_kernel<<<aggGrid, 256, 0, stream>>>(xhi, rowptr, esrc, aghi, aglo, N_NODES);
    gemm_planes<128, true, true><<<gemmGrid, 256, 0, stream>>>(
        aghi, aglo, xhi, xlo, Wl1p, Wr1p, b1, nullptr, xhi, xlo, N_NODES);
    // layer 2: x -> out (f32, no ReLU, DOUT=64)
    agg_kernel<<<aggGrid, 256, 0, stream>>>(xhi, rowptr, esrc, aghi, aglo, N_NODES);
    gemm_planes<64, false, false><<<gemmGrid, 256, 0, stream>>>(
        aghi, aglo, xhi, xlo, Wl2p, Wr2p, b2, outp, nullptr, nullptr, N_NODES);
}

// Round 13
// 286.211 us; speedup vs baseline: 1.6001x; 1.0321x over previous
//
#include <hip/hip_runtime.h>

#define N_NODES 50000
#define N_EDGES 800000
#define NBUCK 196    // dst>>8 -> 0..195
#define NHIST 98     // histogram blocks (8192 edges each)

typedef __attribute__((ext_vector_type(8))) short short8;
typedef __attribute__((ext_vector_type(4))) float f32x4;
typedef __attribute__((ext_vector_type(4))) unsigned short ushort4v;
typedef __attribute__((ext_vector_type(8))) unsigned short ushort8v;

// ---------------- split-bf16 helpers ----------------
// f32 = hi(bf16) + lo(bf16) + O(2^-33). Self path uses Ahi*Bhi+Ahi*Blo+Alo*Bhi;
// agg path (already bf16-rounded gather) uses Ahi*Bhi+Ahi*Blo only.

__device__ inline void split_bf16(float f, unsigned short& hi, unsigned short& lo) {
    union { float f; unsigned u; } a; a.f = f;
    unsigned r = (a.u + 0x7fffu + ((a.u >> 16) & 1u)) >> 16;  // RNE to bf16
    hi = (unsigned short)r;
    union { unsigned u; float f; } b; b.u = r << 16;
    union { float f; unsigned u; } c; c.f = f - b.f;
    unsigned r2 = (c.u + 0x7fffu + ((c.u >> 16) & 1u)) >> 16;
    lo = (unsigned short)r2;
}

__device__ inline unsigned short f2bf(float f) {
    union { float f; unsigned u; } a; a.f = f;
    return (unsigned short)((a.u + 0x7fffu + ((a.u >> 16) & 1u)) >> 16);
}

__device__ inline float bf2f(unsigned short u) {
    union { unsigned u; float f; } a; a.u = (unsigned)u << 16; return a.f;
}

// ---------------- prep: pack(W) + split(x) + bucket histogram ----------------
// IDENTICAL to the R10-passed version (known-good on this infra).
// blocks [0,320): pack 6 weight mats into B-fragment hi/lo planes.
// blocks [320,6570): split x into hi/lo bf16 planes (16B/thread).
// blocks [6570,6668): bucket histogram, 8192 edges/block, per-block LDS hist
//   written PLAIN to blkhist[blk][196] (no global atomics, no pre-zeroing).

__global__ void prep_kernel(const float* __restrict__ W0, const float* __restrict__ W1,
                            const float* __restrict__ W2, const float* __restrict__ W3,
                            const float* __restrict__ W4, const float* __restrict__ W5,
                            unsigned short* __restrict__ wout,
                            const float* __restrict__ x, unsigned short* __restrict__ xhi,
                            unsigned short* __restrict__ xlo,
                            const int* __restrict__ dst, int* __restrict__ blkhist) {
    __shared__ int lhist[NBUCK];
    if (blockIdx.x < 320) {
        int t = blockIdx.x * 256 + threadIdx.x;  // 0..81919
        const float* W; int D, local, half; size_t base;
        if (t < 65536) {
            int mat = t >> 14; local = t & 16383; D = 128; half = 16384;
            base = (size_t)mat * 32768;
            W = mat == 0 ? W0 : mat == 1 ? W1 : mat == 2 ? W2 : W3;
        } else {
            int m = (t - 65536) >> 13; local = (t - 65536) & 8191; D = 64; half = 8192;
            base = 131072 + (size_t)m * 16384;
            W = m == 0 ? W4 : W5;
        }
        int j = local & 7, lane = (local >> 3) & 63, ks = (local >> 9) & 3, ct = local >> 11;
        int k = ks * 32 + ((lane >> 4) << 3) + j;
        int n = (ct << 4) + (lane & 15);
        unsigned short hi, lo;
        split_bf16(W[k * D + n], hi, lo);
        wout[base + local] = hi;
        wout[base + half + local] = lo;
    } else if (blockIdx.x < 6570) {
        int t = (blockIdx.x - 320) * 256 + threadIdx.x;  // one float4 per thread
        if (t >= N_NODES * 32) return;
        float4 v = *(const float4*)(x + (size_t)t * 4);
        float vv[4] = {v.x, v.y, v.z, v.w};
        ushort4v h, l;
#pragma unroll
        for (int j = 0; j < 4; ++j) {
            unsigned short a, b;
            split_bf16(vv[j], a, b);
            h[j] = a; l[j] = b;
        }
        *(ushort4v*)(xhi + (size_t)t * 4) = h;
        *(ushort4v*)(xlo + (size_t)t * 4) = l;
    } else {
        const int hb = blockIdx.x - 6570;
        const int base = hb * 8192;
        if (threadIdx.x < NBUCK) lhist[threadIdx.x] = 0;
        __syncthreads();
#pragma unroll
        for (int i = 0; i < 32; ++i) {
            int e = base + i * 256 + threadIdx.x;
            if (e < N_EDGES) atomicAdd(&lhist[dst[e] >> 8], 1);
        }
        __syncthreads();
        if (threadIdx.x < NBUCK) blkhist[hb * NBUCK + threadIdx.x] = lhist[threadIdx.x];
    }
}

// ---------------- bucket scan (1 block): blkhist -> bucketBase/bucketCur -----

__global__ void scan_sums_kernel(const int* __restrict__ blkhist,
                                 int* __restrict__ bucketBase, int* __restrict__ bucketCur,
                                 int* __restrict__ rowptr) {
    __shared__ int s[256];
    int tid = threadIdx.x;
    int v = 0;
    if (tid < NBUCK)
        for (int h = 0; h < NHIST; ++h) v += blkhist[h * NBUCK + tid];
    s[tid] = v;
    __syncthreads();
    for (int off = 1; off < 256; off <<= 1) {
        int t = (tid >= off) ? s[tid - off] : 0;
        __syncthreads();
        s[tid] += t;
        __syncthreads();
    }
    if (tid < NBUCK) {
        int b = s[tid] - v;
        bucketBase[tid] = b;
        bucketCur[tid] = b;
    }
    if (tid == 0) { bucketBase[NBUCK] = N_EDGES; rowptr[N_NODES] = N_EDGES; }
}

// ---------------- edge partition into 196 buckets (LDS-staged, coalesced) ----
// Direct 4B random scatter = 64B-line write-allocate each (52MB for 3.2MB, R7).
// Stage-sort 2048 edges in LDS, write runs coalesced. Packed (dst<<16)|src.

__global__ __launch_bounds__(256) void partition_kernel(
    const int* __restrict__ src, const int* __restrict__ dst,
    int* __restrict__ bucketCur, unsigned int* __restrict__ ebuf, int E) {
    __shared__ int hist[NBUCK], binoff[NBUCK], bincur[NBUCK], runstart[NBUCK];
    __shared__ int scanbuf[256];
    __shared__ unsigned int sortbuf[2048];
    const int tid = threadIdx.x;
    const int base = blockIdx.x * 2048;
    if (tid < NBUCK) hist[tid] = 0;
    __syncthreads();
    int myb[8]; unsigned int myp[8];
#pragma unroll
    for (int i = 0; i < 8; ++i) {
        int e = base + i * 256 + tid;
        if (e < E) {
            int d = dst[e], s = src[e];
            myb[i] = d >> 8;
            myp[i] = ((unsigned)d << 16) | (unsigned)s;
            atomicAdd(&hist[myb[i]], 1);
        } else myb[i] = -1;
    }
    __syncthreads();
    int v = (tid < NBUCK) ? hist[tid] : 0;
    scanbuf[tid] = v;
    __syncthreads();
    for (int off = 1; off < 256; off <<= 1) {
        int t = (tid >= off) ? scanbuf[tid - off] : 0;
        __syncthreads();
        scanbuf[tid] += t;
        __syncthreads();
    }
    if (tid < NBUCK) {
        binoff[tid] = scanbuf[tid] - v;
        bincur[tid] = 0;
        runstart[tid] = atomicAdd(&bucketCur[tid], v);
    }
    __syncthreads();
#pragma unroll
    for (int i = 0; i < 8; ++i) {
        if (myb[i] >= 0) {
            int r = atomicAdd(&bincur[myb[i]], 1);
            sortbuf[binoff[myb[i]] + r] = myp[i];
        }
    }
    __syncthreads();
    int nloc = E - base; if (nloc > 2048) nloc = 2048;
#pragma unroll
    for (int i = 0; i < 8; ++i) {
        int idx = i * 256 + tid;
        if (idx < nloc) {
            unsigned int p = sortbuf[idx];
            int b = p >> 24;   // dst>>8
            ebuf[runstart[b] + (idx - binoff[b])] = p;
        }
    }
}

// ---------------- fine fill: per bucket, derive rowptr + scatter esrc ---------
// Per-node counts within the bucket are complete (nodes partitioned by dst>>8),
// so rowptr[node] = bucketBase[b] + LDS-scan of in-bucket counts.

__global__ __launch_bounds__(256) void fine_fill_kernel(
    const unsigned int* __restrict__ ebuf, const int* __restrict__ bucketBase,
    int* __restrict__ rowptr, unsigned short* __restrict__ esrc, int n) {
    __shared__ int cnt[256], scanbuf[256], cur[256];
    const int b = blockIdx.x, tid = threadIdx.x;
    const int nbase = b << 8;
    cnt[tid] = 0;
    __syncthreads();
    const int lo = bucketBase[b], hi = bucketBase[b + 1];
    for (int k = lo + tid; k < hi; k += 256)
        atomicAdd(&cnt[(ebuf[k] >> 16) & 255], 1);
    __syncthreads();
    int v = cnt[tid];
    scanbuf[tid] = v;
    __syncthreads();
    for (int off = 1; off < 256; off <<= 1) {
        int t = (tid >= off) ? scanbuf[tid - off] : 0;
        __syncthreads();
        scanbuf[tid] += t;
        __syncthreads();
    }
    int start = lo + scanbuf[tid] - v;   // exclusive
    if (nbase + tid < n) rowptr[nbase + tid] = start;
    cur[tid] = start;
    __syncthreads();
    for (int k = lo + tid; k < hi; k += 256) {
        unsigned int p = ebuf[k];
        int pos = atomicAdd(&cur[(p >> 16) & 255], 1);
        esrc[pos] = (unsigned short)(p & 0xFFFFu);
    }
}

// ---------------- mean aggregation (CSR gather, bf16-hi plane) ----------------
// 16 lanes per node (ushort8v = 16B/lane), 50k independent groups, 4-way
// interleaved neighbor loop. Output: hi plane ONLY (the gather is already
// bf16-rounded; the mean's lo-residual is noise -> dropped, saves 12.8MB/layer).

__global__ __launch_bounds__(256, 6) void agg_kernel(
    const unsigned short* __restrict__ Hhi, const int* __restrict__ rowptr,
    const unsigned short* __restrict__ esrc,
    unsigned short* __restrict__ Ahi, int n) {
    int g = (blockIdx.x * blockDim.x + threadIdx.x) >> 4;
    int l16 = threadIdx.x & 15;
    if (g >= n) return;
    int beg = rowptr[g], end = rowptr[g + 1];
    float a0[8] = {0,0,0,0,0,0,0,0}, a1[8] = {0,0,0,0,0,0,0,0};
    float a2[8] = {0,0,0,0,0,0,0,0}, a3[8] = {0,0,0,0,0,0,0,0};
    int k = beg;
    for (; k + 4 <= end; k += 4) {
        int e0 = esrc[k], e1 = esrc[k + 1], e2 = esrc[k + 2], e3 = esrc[k + 3];
        ushort8v v0 = *(const ushort8v*)(Hhi + (size_t)e0 * 128 + l16 * 8);
        ushort8v v1 = *(const ushort8v*)(Hhi + (size_t)e1 * 128 + l16 * 8);
        ushort8v v2 = *(const ushort8v*)(Hhi + (size_t)e2 * 128 + l16 * 8);
        ushort8v v3 = *(const ushort8v*)(Hhi + (size_t)e3 * 128 + l16 * 8);
#pragma unroll
        for (int j = 0; j < 8; ++j) {
            a0[j] += bf2f(v0[j]); a1[j] += bf2f(v1[j]);
            a2[j] += bf2f(v2[j]); a3[j] += bf2f(v3[j]);
        }
    }
    for (; k < end; ++k) {
        int e0 = esrc[k];
        ushort8v v0 = *(const ushort8v*)(Hhi + (size_t)e0 * 128 + l16 * 8);
#pragma unroll
        for (int j = 0; j < 8; ++j) a0[j] += bf2f(v0[j]);
    }
    float inv = (end > beg) ? 1.0f / (float)(end - beg) : 0.0f;
    ushort8v mh;
#pragma unroll
    for (int j = 0; j < 8; ++j)
        mh[j] = f2bf((a0[j] + a1[j] + a2[j] + a3[j]) * inv);
    *(ushort8v*)(Ahi + (size_t)g * 128 + l16 * 8) = mh;
}

// ---------------- dual GEMM via MFMA (plane inputs, verbatim staging) --------
// out = A1@W1 + A2@W2 + b (opt ReLU). A1 = agg (hi only, 2 MFMAs: hi*bhi +
// hi*blo); A2 = self (hi+lo, 3 MFMAs). BM=32, 256 thr = 4 waves.
// In-place safe: block stages only its own 32 rows before writing them.

template <int DOUT, bool RELU, bool SPLIT_OUT>
__global__ __launch_bounds__(256, 4) void gemm_planes(
    const unsigned short* __restrict__ A1hi,
    const unsigned short* __restrict__ A2hi, const unsigned short* __restrict__ A2lo,
    const unsigned short* __restrict__ B1p, const unsigned short* __restrict__ B2p,
    const float* __restrict__ bias, float* __restrict__ outf,
    unsigned short* __restrict__ outhi, unsigned short* __restrict__ outlo, int M) {
    constexpr int K = 128, BM = 32, KS = 4, CT = DOUT / 16, CPW = CT / 4;
    constexpr int PITCH = K + 8;
    constexpr int HALF = CT * KS * 512;
    __shared__ unsigned short As[3][BM * PITCH];  // [agg-hi, self-hi, self-lo]

    const int tid = threadIdx.x;
    const int r0 = blockIdx.x * BM;

    const unsigned short* __restrict__ srcs[3] = {A1hi, A2hi, A2lo};
#pragma unroll
    for (int s = 0; s < 3; ++s) {
#pragma unroll
        for (int c = 0; c < 2; ++c) {
            int chunk = tid + c * 256;
            int row = chunk >> 4;
            int c8 = (chunk & 15) * 8;
            int grow = r0 + row; if (grow >= M) grow = M - 1;
            *(ushort8v*)(&As[s][row * PITCH + c8]) =
                *(const ushort8v*)(srcs[s] + (size_t)grow * K + c8);
        }
    }
    __syncthreads();

    const int wave = tid >> 6, lane = tid & 63;
    const int rl = lane & 15, quad = lane >> 4;

    f32x4 acc[2][CPW];
#pragma unroll
    for (int c = 0; c < CPW; ++c) {
        float bv = bias[(wave * CPW + c) * 16 + rl];
        acc[0][c] = (f32x4){bv, bv, bv, bv};
        acc[1][c] = acc[0][c];
    }

#pragma unroll
    for (int ks = 0; ks < KS; ++ks) {
        short8 a_ag[2], a_sh[2][2];
#pragma unroll
        for (int rt = 0; rt < 2; ++rt) {
            int off = (rt * 16 + rl) * PITCH + ks * 32 + quad * 8;
            a_ag[rt]    = *(const short8*)(&As[0][off]);
            a_sh[rt][0] = *(const short8*)(&As[1][off]);
            a_sh[rt][1] = *(const short8*)(&As[2][off]);
        }
        short8 b1[CPW][2], b2[CPW][2];
#pragma unroll
        for (int c = 0; c < CPW; ++c) {
            size_t boff = (((wave * CPW + c) * KS + ks) * 64 + lane) * 8;
#pragma unroll
            for (int p = 0; p < 2; ++p) {
                b1[c][p] = *(const short8*)(B1p + p * HALF + boff);
                b2[c][p] = *(const short8*)(B2p + p * HALF + boff);
            }
        }
#pragma unroll
        for (int rt = 0; rt < 2; ++rt)
#pragma unroll
            for (int c = 0; c < CPW; ++c) {
                acc[rt][c] = __builtin_amdgcn_mfma_f32_16x16x32_bf16(a_ag[rt],    b1[c][0], acc[rt][c], 0, 0, 0);
                acc[rt][c] = __builtin_amdgcn_mfma_f32_16x16x32_bf16(a_ag[rt],    b1[c][1], acc[rt][c], 0, 0, 0);
                acc[rt][c] = __builtin_amdgcn_mfma_f32_16x16x32_bf16(a_sh[rt][0], b2[c][0], acc[rt][c], 0, 0, 0);
                acc[rt][c] = __builtin_amdgcn_mfma_f32_16x16x32_bf16(a_sh[rt][0], b2[c][1], acc[rt][c], 0, 0, 0);
                acc[rt][c] = __builtin_amdgcn_mfma_f32_16x16x32_bf16(a_sh[rt][1], b2[c][0], acc[rt][c], 0, 0, 0);
            }
    }

    // ---- epilogue: C/D layout col=lane&15, row=quad*4+reg ----
#pragma unroll
    for (int rt = 0; rt < 2; ++rt)
#pragma unroll
        for (int c = 0; c < CPW; ++c) {
            int col = (wave * CPW + c) * 16 + rl;
            int rowb = r0 + rt * 16 + quad * 4;
#pragma unroll
            for (int r = 0; r < 4; ++r) {
                int rr = rowb + r;
                if (rr < M) {
                    float vv = acc[rt][c][r];
                    if (RELU) vv = fmaxf(vv, 0.f);
                    if (SPLIT_OUT) {
                        unsigned short h, l;
                        split_bf16(vv, h, l);
                        outhi[(size_t)rr * DOUT + col] = h;
                        outlo[(size_t)rr * DOUT + col] = l;
                    } else {
                        outf[(size_t)rr * DOUT + col] = vv;
                    }
                }
            }
        }
}

// ---------------- launch ----------------

extern "C" void kernel_launch(void* const* d_in, const int* in_sizes, int n_in,
                              void* d_out, int out_size, void* d_ws, size_t ws_size,
                              hipStream_t stream) {
    const float* x   = (const float*)d_in[0];
    const int* eidx  = (const int*)d_in[1];
    const int* src   = eidx;             // edge_index[0]
    const int* dst   = eidx + N_EDGES;   // edge_index[1]
    const float* Wl0 = (const float*)d_in[2];
    const float* b0  = (const float*)d_in[3];
    const float* Wr0 = (const float*)d_in[4];
    const float* Wl1 = (const float*)d_in[5];
    const float* b1  = (const float*)d_in[6];
    const float* Wr1 = (const float*)d_in[7];
    const float* Wl2 = (const float*)d_in[8];
    const float* b2  = (const float*)d_in[9];
    const float* Wr2 = (const float*)d_in[10];
    float* outp = (float*)d_out;

    // workspace (~41 MB)
    unsigned short* xhi  = (unsigned short*)d_ws;           // N*128 each
    unsigned short* xlo  = xhi + (size_t)N_NODES * 128;
    unsigned short* aghi = xlo + (size_t)N_NODES * 128;
    unsigned int* ebuf = (unsigned int*)aghi;               // ALIAS: consumed before agg writes
    int* rowptr    = (int*)(aghi + (size_t)N_NODES * 128);  // 50016
    int* blkhist   = rowptr + 50016;                        // 98*196 = 19208
    int* bucketBase= blkhist + 19208;                       // 256 (197 used)
    int* bucketCur = bucketBase + 256;                      // 256
    unsigned short* esrc  = (unsigned short*)(bucketCur + 256); // E ushort = 1.6MB
    unsigned short* packw = esrc + N_EDGES;                 // 163840 bf16 (16B-aligned)
    unsigned short* Wl0p = packw;
    unsigned short* Wr0p = packw + 32768;
    unsigned short* Wl1p = packw + 65536;
    unsigned short* Wr1p = packw + 98304;
    unsigned short* Wl2p = packw + 131072;
    unsigned short* Wr2p = packw + 147456;

    // --- prep (pack W + split x + per-block bucket hist; no atomics to global) ---
    prep_kernel<<<6668, 256, 0, stream>>>(Wl0, Wr0, Wl1, Wr1, Wl2, Wr2, packw,
                                          x, xhi, xlo, dst, blkhist);
    // --- bucket scan (1 block) -> bucketBase/bucketCur, rowptr[N]=E ---
    scan_sums_kernel<<<1, 256, 0, stream>>>(blkhist, bucketBase, bucketCur, rowptr);
    // --- partition edges into buckets (coalesced), then per-bucket CSR ---
    partition_kernel<<<(N_EDGES + 2047) / 2048, 256, 0, stream>>>(src, dst, bucketCur, ebuf, N_EDGES);
    fine_fill_kernel<<<NBUCK, 256, 0, stream>>>(ebuf, bucketBase, rowptr, esrc, N_NODES);

    const int aggGrid = (N_NODES * 16 + 255) / 256;   // 3125
    const int gemmGrid = (N_NODES + 31) / 32;         // 1563

    // layer 0: x -> x (in place, ReLU)
    agg_kernel<<<aggGrid, 256, 0, stream>>>(xhi, rowptr, esrc, aghi, N_NODES);
    gemm_planes<128, true, true><<<gemmGrid, 256, 0, stream>>>(
        aghi, xhi, xlo, Wl0p, Wr0p, b0, nullptr, xhi, xlo, N_NODES);
    // layer 1: x -> x (in place, ReLU)
    agg_kernel<<<aggGrid, 256, 0, stream>>>(xhi, rowptr, esrc, aghi, N_NODES);
    gemm_planes<128, true, true><<<gemmGrid, 256, 0, stream>>>(
        aghi, xhi, xlo, Wl1p, Wr1p, b1, nullptr, xhi, xlo, N_NODES);
    // layer 2: x -> out (f32, no ReLU, DOUT=64)
    agg_kernel<<<aggGrid, 256, 0, stream>>>(xhi, rowptr, esrc, aghi, N_NODES);
    gemm_planes<64, false, false><<<gemmGrid, 256, 0, stream>>>(
        aghi, xhi, xlo, Wl2p, Wr2p, b2, outp, nullptr, nullptr, N_NODES);
}

// Round 14
// 282.888 us; speedup vs baseline: 1.6189x; 1.0117x over previous
//
#include <hip/hip_runtime.h>

#define N_NODES 50000
#define N_EDGES 800000
#define NBUCK 196    // dst>>8 -> 0..195
#define NHIST 196    // histogram blocks (4096 edges each)

typedef __attribute__((ext_vector_type(8))) short short8;
typedef __attribute__((ext_vector_type(4))) float f32x4;
typedef __attribute__((ext_vector_type(4))) unsigned short ushort4v;
typedef __attribute__((ext_vector_type(8))) unsigned short ushort8v;

// ---------------- split-bf16 helpers ----------------
// f32 = hi(bf16) + lo(bf16) + O(2^-33). Self path uses Ahi*Bhi+Ahi*Blo+Alo*Bhi;
// agg path (already bf16-rounded gather) uses Ahi*Bhi+Ahi*Blo only.

__device__ inline void split_bf16(float f, unsigned short& hi, unsigned short& lo) {
    union { float f; unsigned u; } a; a.f = f;
    unsigned r = (a.u + 0x7fffu + ((a.u >> 16) & 1u)) >> 16;  // RNE to bf16
    hi = (unsigned short)r;
    union { unsigned u; float f; } b; b.u = r << 16;
    union { float f; unsigned u; } c; c.f = f - b.f;
    unsigned r2 = (c.u + 0x7fffu + ((c.u >> 16) & 1u)) >> 16;
    lo = (unsigned short)r2;
}

__device__ inline unsigned short f2bf(float f) {
    union { float f; unsigned u; } a; a.f = f;
    return (unsigned short)((a.u + 0x7fffu + ((a.u >> 16) & 1u)) >> 16);
}

__device__ inline float bf2f(unsigned short u) {
    union { unsigned u; float f; } a; a.u = (unsigned)u << 16; return a.f;
}

// ---------------- prep: pack(W) + split(x) + bucket histogram ----------------
// blocks [0,320): pack 6 weight mats into B-fragment hi/lo planes.
// blocks [320,1883): split x into hi/lo planes, 64B-read/thread (R10 prep was
//   block-churn-bound at 16B/thread).
// blocks [1883,2079): bucket histogram, 4096 edges/block, per-block LDS hist
//   written PLAIN to blkhist[blk][196] (no global atomics, no pre-zeroing).

__global__ void prep_kernel(const float* __restrict__ W0, const float* __restrict__ W1,
                            const float* __restrict__ W2, const float* __restrict__ W3,
                            const float* __restrict__ W4, const float* __restrict__ W5,
                            unsigned short* __restrict__ wout,
                            const float* __restrict__ x, unsigned short* __restrict__ xhi,
                            unsigned short* __restrict__ xlo,
                            const int* __restrict__ dst, int* __restrict__ blkhist) {
    __shared__ int lhist[NBUCK];
    if (blockIdx.x < 320) {
        int t = blockIdx.x * 256 + threadIdx.x;  // 0..81919
        const float* W; int D, local, half; size_t base;
        if (t < 65536) {
            int mat = t >> 14; local = t & 16383; D = 128; half = 16384;
            base = (size_t)mat * 32768;
            W = mat == 0 ? W0 : mat == 1 ? W1 : mat == 2 ? W2 : W3;
        } else {
            int m = (t - 65536) >> 13; local = (t - 65536) & 8191; D = 64; half = 8192;
            base = 131072 + (size_t)m * 16384;
            W = m == 0 ? W4 : W5;
        }
        int j = local & 7, lane = (local >> 3) & 63, ks = (local >> 9) & 3, ct = local >> 11;
        int k = ks * 32 + ((lane >> 4) << 3) + j;
        int n = (ct << 4) + (lane & 15);
        unsigned short hi, lo;
        split_bf16(W[k * D + n], hi, lo);
        wout[base + local] = hi;
        wout[base + half + local] = lo;
    } else if (blockIdx.x < 1883) {
        int t = (blockIdx.x - 320) * 256 + threadIdx.x;  // one 16-float chunk/thread
        if (t >= N_NODES * 8) return;                    // 50000*128/16 = 400000
        const float* p = x + (size_t)t * 16;
#pragma unroll
        for (int half = 0; half < 2; ++half) {
            float4 v0 = *(const float4*)(p + half * 8);
            float4 v1 = *(const float4*)(p + half * 8 + 4);
            float vv[8] = {v0.x, v0.y, v0.z, v0.w, v1.x, v1.y, v1.z, v1.w};
            ushort8v h, l;
#pragma unroll
            for (int j = 0; j < 8; ++j) {
                unsigned short a, b;
                split_bf16(vv[j], a, b);
                h[j] = a; l[j] = b;
            }
            *(ushort8v*)(xhi + (size_t)t * 16 + half * 8) = h;
            *(ushort8v*)(xlo + (size_t)t * 16 + half * 8) = l;
        }
    } else {
        const int hb = blockIdx.x - 1883;
        const int base = hb * 4096;
        if (threadIdx.x < NBUCK) lhist[threadIdx.x] = 0;
        __syncthreads();
#pragma unroll
        for (int i = 0; i < 16; ++i) {
            int e = base + i * 256 + threadIdx.x;
            if (e < N_EDGES) atomicAdd(&lhist[dst[e] >> 8], 1);
        }
        __syncthreads();
        if (threadIdx.x < NBUCK) blkhist[hb * NBUCK + threadIdx.x] = lhist[threadIdx.x];
    }
}

// ---------------- bucket scan (1 block): blkhist -> bucketBase/bucketCur -----

__global__ void scan_sums_kernel(const int* __restrict__ blkhist,
                                 int* __restrict__ bucketBase, int* __restrict__ bucketCur,
                                 int* __restrict__ rowptr) {
    __shared__ int s[256];
    int tid = threadIdx.x;
    int v = 0;
    if (tid < NBUCK)
        for (int h = 0; h < NHIST; ++h) v += blkhist[h * NBUCK + tid];
    s[tid] = v;
    __syncthreads();
    for (int off = 1; off < 256; off <<= 1) {
        int t = (tid >= off) ? s[tid - off] : 0;
        __syncthreads();
        s[tid] += t;
        __syncthreads();
    }
    if (tid < NBUCK) {
        int b = s[tid] - v;
        bucketBase[tid] = b;
        bucketCur[tid] = b;
    }
    if (tid == 0) { bucketBase[NBUCK] = N_EDGES; rowptr[N_NODES] = N_EDGES; }
}

// ---------------- edge partition into 196 buckets (LDS-staged, coalesced) ----
// Direct 4B random scatter = 64B-line write-allocate each (52MB for 3.2MB, R7).
// Stage-sort 2048 edges in LDS, write runs coalesced. Packed (dst<<16)|src.

__global__ __launch_bounds__(256) void partition_kernel(
    const int* __restrict__ src, const int* __restrict__ dst,
    int* __restrict__ bucketCur, unsigned int* __restrict__ ebuf, int E) {
    __shared__ int hist[NBUCK], binoff[NBUCK], bincur[NBUCK], runstart[NBUCK];
    __shared__ int scanbuf[256];
    __shared__ unsigned int sortbuf[2048];
    const int tid = threadIdx.x;
    const int base = blockIdx.x * 2048;
    if (tid < NBUCK) hist[tid] = 0;
    __syncthreads();
    int myb[8]; unsigned int myp[8];
#pragma unroll
    for (int i = 0; i < 8; ++i) {
        int e = base + i * 256 + tid;
        if (e < E) {
            int d = dst[e], s = src[e];
            myb[i] = d >> 8;
            myp[i] = ((unsigned)d << 16) | (unsigned)s;
            atomicAdd(&hist[myb[i]], 1);
        } else myb[i] = -1;
    }
    __syncthreads();
    int v = (tid < NBUCK) ? hist[tid] : 0;
    scanbuf[tid] = v;
    __syncthreads();
    for (int off = 1; off < 256; off <<= 1) {
        int t = (tid >= off) ? scanbuf[tid - off] : 0;
        __syncthreads();
        scanbuf[tid] += t;
        __syncthreads();
    }
    if (tid < NBUCK) {
        binoff[tid] = scanbuf[tid] - v;
        bincur[tid] = 0;
        runstart[tid] = atomicAdd(&bucketCur[tid], v);
    }
    __syncthreads();
#pragma unroll
    for (int i = 0; i < 8; ++i) {
        if (myb[i] >= 0) {
            int r = atomicAdd(&bincur[myb[i]], 1);
            sortbuf[binoff[myb[i]] + r] = myp[i];
        }
    }
    __syncthreads();
    int nloc = E - base; if (nloc > 2048) nloc = 2048;
#pragma unroll
    for (int i = 0; i < 8; ++i) {
        int idx = i * 256 + tid;
        if (idx < nloc) {
            unsigned int p = sortbuf[idx];
            int b = p >> 24;   // dst>>8
            ebuf[runstart[b] + (idx - binoff[b])] = p;
        }
    }
}

// ---------------- fine fill: per bucket, derive rowptr + scatter esrc ---------
// Per-node counts within the bucket are complete (nodes partitioned by dst>>8),
// so rowptr[node] = bucketBase[b] + LDS-scan of in-bucket counts.

__global__ __launch_bounds__(256) void fine_fill_kernel(
    const unsigned int* __restrict__ ebuf, const int* __restrict__ bucketBase,
    int* __restrict__ rowptr, unsigned short* __restrict__ esrc, int n) {
    __shared__ int cnt[256], scanbuf[256], cur[256];
    const int b = blockIdx.x, tid = threadIdx.x;
    const int nbase = b << 8;
    cnt[tid] = 0;
    __syncthreads();
    const int lo = bucketBase[b], hi = bucketBase[b + 1];
    for (int k = lo + tid; k < hi; k += 256)
        atomicAdd(&cnt[(ebuf[k] >> 16) & 255], 1);
    __syncthreads();
    int v = cnt[tid];
    scanbuf[tid] = v;
    __syncthreads();
    for (int off = 1; off < 256; off <<= 1) {
        int t = (tid >= off) ? scanbuf[tid - off] : 0;
        __syncthreads();
        scanbuf[tid] += t;
        __syncthreads();
    }
    int start = lo + scanbuf[tid] - v;   // exclusive
    if (nbase + tid < n) rowptr[nbase + tid] = start;
    cur[tid] = start;
    __syncthreads();
    for (int k = lo + tid; k < hi; k += 256) {
        unsigned int p = ebuf[k];
        int pos = atomicAdd(&cur[(p >> 16) & 255], 1);
        esrc[pos] = (unsigned short)(p & 0xFFFFu);
    }
}

// ---------------- mean aggregation (CSR gather, bf16-hi plane) ----------------
// 16 lanes per node (ushort8v = 16B/lane), 50k independent groups, 4-way
// interleaved neighbor loop. Output: hi plane ONLY (the gather is already
// bf16-rounded; the mean's lo-residual is noise -> dropped, saves 12.8MB/layer).

__global__ __launch_bounds__(256, 6) void agg_kernel(
    const unsigned short* __restrict__ Hhi, const int* __restrict__ rowptr,
    const unsigned short* __restrict__ esrc,
    unsigned short* __restrict__ Ahi, int n) {
    int g = (blockIdx.x * blockDim.x + threadIdx.x) >> 4;
    int l16 = threadIdx.x & 15;
    if (g >= n) return;
    int beg = rowptr[g], end = rowptr[g + 1];
    float a0[8] = {0,0,0,0,0,0,0,0}, a1[8] = {0,0,0,0,0,0,0,0};
    float a2[8] = {0,0,0,0,0,0,0,0}, a3[8] = {0,0,0,0,0,0,0,0};
    int k = beg;
    for (; k + 4 <= end; k += 4) {
        int e0 = esrc[k], e1 = esrc[k + 1], e2 = esrc[k + 2], e3 = esrc[k + 3];
        ushort8v v0 = *(const ushort8v*)(Hhi + (size_t)e0 * 128 + l16 * 8);
        ushort8v v1 = *(const ushort8v*)(Hhi + (size_t)e1 * 128 + l16 * 8);
        ushort8v v2 = *(const ushort8v*)(Hhi + (size_t)e2 * 128 + l16 * 8);
        ushort8v v3 = *(const ushort8v*)(Hhi + (size_t)e3 * 128 + l16 * 8);
#pragma unroll
        for (int j = 0; j < 8; ++j) {
            a0[j] += bf2f(v0[j]); a1[j] += bf2f(v1[j]);
            a2[j] += bf2f(v2[j]); a3[j] += bf2f(v3[j]);
        }
    }
    for (; k < end; ++k) {
        int e0 = esrc[k];
        ushort8v v0 = *(const ushort8v*)(Hhi + (size_t)e0 * 128 + l16 * 8);
#pragma unroll
        for (int j = 0; j < 8; ++j) a0[j] += bf2f(v0[j]);
    }
    float inv = (end > beg) ? 1.0f / (float)(end - beg) : 0.0f;
    ushort8v mh;
#pragma unroll
    for (int j = 0; j < 8; ++j)
        mh[j] = f2bf((a0[j] + a1[j] + a2[j] + a3[j]) * inv);
    *(ushort8v*)(Ahi + (size_t)g * 128 + l16 * 8) = mh;
}

// ---------------- dual GEMM via MFMA (plane inputs, verbatim staging) --------
// out = A1@W1 + A2@W2 + b (opt ReLU). A1 = agg (hi only, 2 MFMAs: hi*bhi +
// hi*blo); A2 = self (hi+lo, 3 MFMAs). BM=32, 256 thr = 4 waves.
// In-place safe: block stages only its own 32 rows before writing them.

template <int DOUT, bool RELU, bool SPLIT_OUT>
__global__ __launch_bounds__(256, 4) void gemm_planes(
    const unsigned short* __restrict__ A1hi,
    const unsigned short* __restrict__ A2hi, const unsigned short* __restrict__ A2lo,
    const unsigned short* __restrict__ B1p, const unsigned short* __restrict__ B2p,
    const float* __restrict__ bias, float* __restrict__ outf,
    unsigned short* __restrict__ outhi, unsigned short* __restrict__ outlo, int M) {
    constexpr int K = 128, BM = 32, KS = 4, CT = DOUT / 16, CPW = CT / 4;
    constexpr int PITCH = K + 8;
    constexpr int HALF = CT * KS * 512;
    __shared__ unsigned short As[3][BM * PITCH];  // [agg-hi, self-hi, self-lo]

    const int tid = threadIdx.x;
    const int r0 = blockIdx.x * BM;

    const unsigned short* __restrict__ srcs[3] = {A1hi, A2hi, A2lo};
#pragma unroll
    for (int s = 0; s < 3; ++s) {
#pragma unroll
        for (int c = 0; c < 2; ++c) {
            int chunk = tid + c * 256;
            int row = chunk >> 4;
            int c8 = (chunk & 15) * 8;
            int grow = r0 + row; if (grow >= M) grow = M - 1;
            *(ushort8v*)(&As[s][row * PITCH + c8]) =
                *(const ushort8v*)(srcs[s] + (size_t)grow * K + c8);
        }
    }
    __syncthreads();

    const int wave = tid >> 6, lane = tid & 63;
    const int rl = lane & 15, quad = lane >> 4;

    f32x4 acc[2][CPW];
#pragma unroll
    for (int c = 0; c < CPW; ++c) {
        float bv = bias[(wave * CPW + c) * 16 + rl];
        acc[0][c] = (f32x4){bv, bv, bv, bv};
        acc[1][c] = acc[0][c];
    }

#pragma unroll
    for (int ks = 0; ks < KS; ++ks) {
        short8 a_ag[2], a_sh[2][2];
#pragma unroll
        for (int rt = 0; rt < 2; ++rt) {
            int off = (rt * 16 + rl) * PITCH + ks * 32 + quad * 8;
            a_ag[rt]    = *(const short8*)(&As[0][off]);
            a_sh[rt][0] = *(const short8*)(&As[1][off]);
            a_sh[rt][1] = *(const short8*)(&As[2][off]);
        }
        short8 b1[CPW][2], b2[CPW][2];
#pragma unroll
        for (int c = 0; c < CPW; ++c) {
            size_t boff = (((wave * CPW + c) * KS + ks) * 64 + lane) * 8;
#pragma unroll
            for (int p = 0; p < 2; ++p) {
                b1[c][p] = *(const short8*)(B1p + p * HALF + boff);
                b2[c][p] = *(const short8*)(B2p + p * HALF + boff);
            }
        }
#pragma unroll
        for (int rt = 0; rt < 2; ++rt)
#pragma unroll
            for (int c = 0; c < CPW; ++c) {
                acc[rt][c] = __builtin_amdgcn_mfma_f32_16x16x32_bf16(a_ag[rt],    b1[c][0], acc[rt][c], 0, 0, 0);
                acc[rt][c] = __builtin_amdgcn_mfma_f32_16x16x32_bf16(a_ag[rt],    b1[c][1], acc[rt][c], 0, 0, 0);
                acc[rt][c] = __builtin_amdgcn_mfma_f32_16x16x32_bf16(a_sh[rt][0], b2[c][0], acc[rt][c], 0, 0, 0);
                acc[rt][c] = __builtin_amdgcn_mfma_f32_16x16x32_bf16(a_sh[rt][0], b2[c][1], acc[rt][c], 0, 0, 0);
                acc[rt][c] = __builtin_amdgcn_mfma_f32_16x16x32_bf16(a_sh[rt][1], b2[c][0], acc[rt][c], 0, 0, 0);
            }
    }

    // ---- epilogue: C/D layout col=lane&15, row=quad*4+reg ----
#pragma unroll
    for (int rt = 0; rt < 2; ++rt)
#pragma unroll
        for (int c = 0; c < CPW; ++c) {
            int col = (wave * CPW + c) * 16 + rl;
            int rowb = r0 + rt * 16 + quad * 4;
#pragma unroll
            for (int r = 0; r < 4; ++r) {
                int rr = rowb + r;
                if (rr < M) {
                    float vv = acc[rt][c][r];
                    if (RELU) vv = fmaxf(vv, 0.f);
                    if (SPLIT_OUT) {
                        unsigned short h, l;
                        split_bf16(vv, h, l);
                        outhi[(size_t)rr * DOUT + col] = h;
                        outlo[(size_t)rr * DOUT + col] = l;
                    } else {
                        outf[(size_t)rr * DOUT + col] = vv;
                    }
                }
            }
        }
}

// ---------------- launch ----------------

extern "C" void kernel_launch(void* const* d_in, const int* in_sizes, int n_in,
                              void* d_out, int out_size, void* d_ws, size_t ws_size,
                              hipStream_t stream) {
    const float* x   = (const float*)d_in[0];
    const int* eidx  = (const int*)d_in[1];
    const int* src   = eidx;             // edge_index[0]
    const int* dst   = eidx + N_EDGES;   // edge_index[1]
    const float* Wl0 = (const float*)d_in[2];
    const float* b0  = (const float*)d_in[3];
    const float* Wr0 = (const float*)d_in[4];
    const float* Wl1 = (const float*)d_in[5];
    const float* b1  = (const float*)d_in[6];
    const float* Wr1 = (const float*)d_in[7];
    const float* Wl2 = (const float*)d_in[8];
    const float* b2  = (const float*)d_in[9];
    const float* Wr2 = (const float*)d_in[10];
    float* outp = (float*)d_out;

    // workspace (~41 MB)
    unsigned short* xhi  = (unsigned short*)d_ws;           // N*128 each
    unsigned short* xlo  = xhi + (size_t)N_NODES * 128;
    unsigned short* aghi = xlo + (size_t)N_NODES * 128;
    unsigned int* ebuf = (unsigned int*)aghi;               // ALIAS: consumed before agg writes
    int* rowptr    = (int*)(aghi + (size_t)N_NODES * 128);  // 50016
    int* blkhist   = rowptr + 50016;                        // 196*196 = 38416
    int* bucketBase= blkhist + 38416;                       // 256 (197 used)
    int* bucketCur = bucketBase + 256;                      // 256
    unsigned short* esrc  = (unsigned short*)(bucketCur + 256); // E ushort = 1.6MB
    unsigned short* packw = esrc + N_EDGES;                 // 163840 bf16 (16B-aligned)
    unsigned short* Wl0p = packw;
    unsigned short* Wr0p = packw + 32768;
    unsigned short* Wl1p = packw + 65536;
    unsigned short* Wr1p = packw + 98304;
    unsigned short* Wl2p = packw + 131072;
    unsigned short* Wr2p = packw + 147456;

    // --- prep (pack W + split x + per-block bucket hist; no atomics to global) ---
    prep_kernel<<<2079, 256, 0, stream>>>(Wl0, Wr0, Wl1, Wr1, Wl2, Wr2, packw,
                                          x, xhi, xlo, dst, blkhist);
    // --- bucket scan (1 block) -> bucketBase/bucketCur, rowptr[N]=E ---
    scan_sums_kernel<<<1, 256, 0, stream>>>(blkhist, bucketBase, bucketCur, rowptr);
    // --- partition edges into buckets (coalesced), then per-bucket CSR ---
    partition_kernel<<<(N_EDGES + 2047) / 2048, 256, 0, stream>>>(src, dst, bucketCur, ebuf, N_EDGES);
    fine_fill_kernel<<<NBUCK, 256, 0, stream>>>(ebuf, bucketBase, rowptr, esrc, N_NODES);

    const int aggGrid = (N_NODES * 16 + 255) / 256;   // 3125
    const int gemmGrid = (N_NODES + 31) / 32;         // 1563

    // layer 0: x -> x (in place, ReLU)
    agg_kernel<<<aggGrid, 256, 0, stream>>>(xhi, rowptr, esrc, aghi, N_NODES);
    gemm_planes<128, true, true><<<gemmGrid, 256, 0, stream>>>(
        aghi, xhi, xlo, Wl0p, Wr0p, b0, nullptr, xhi, xlo, N_NODES);
    // layer 1: x -> x (in place, ReLU)
    agg_kernel<<<aggGrid, 256, 0, stream>>>(xhi, rowptr, esrc, aghi, N_NODES);
    gemm_planes<128, true, true><<<gemmGrid, 256, 0, stream>>>(
        aghi, xhi, xlo, Wl1p, Wr1p, b1, nullptr, xhi, xlo, N_NODES);
    // layer 2: x -> out (f32, no ReLU, DOUT=64)
    agg_kernel<<<aggGrid, 256, 0, stream>>>(xhi, rowptr, esrc, aghi, N_NODES);
    gemm_planes<64, false, false><<<gemmGrid, 256, 0, stream>>>(
        aghi, xhi, xlo, Wl2p, Wr2p, b2, outp, nullptr, nullptr, N_NODES);
}